// Round 21
// baseline (119.234 us; speedup 1.0000x reference)
//
#include <hip/hip_runtime.h>
#include <hip/hip_bf16.h>

// SelfAttention: O = softmax(mask((X_q WQ)(X_k WK)^T/8)) (X_v WV), causal +
// key-padding (V_len) + query (Q_len) masks. B=8 S=1024 D=1024 H=16 Dh=64.
//
// All intermediates FP16. Length-aware skipping + DEVICE COMPACTION for BOTH
// proj tiles and attn q-tiles:
//   - prep builds: alist  = active proj tiles (ordered, W-slab adjacent)
//                  alist2 = active attn (b,qt) entries, qt-DESCENDING
//                  zlist  = inactive (b,qt) entries (out rows zero-filled)
//   - proj/attn launch fixed grids; blocks beyond counts exit immediately.
//   - k/v tiles beyond min(V_len?:S, Q_len) are never computed (never read).
// Pipeline:
//   prep    : X fp32->fp16 + Wt transpose + compaction lists.
//   proj    : compacted 128^2 tiles, BK=32, gload_lds w16, 3 rotating LDS
//             buffers, counted vmcnt(4) + raw s_barrier, XOR swizzle.
//   attn_fwd: compacted single-q-tile flash blocks (4 waves x 16 rows),
//             kf double-buffer + early vf; zero-blocks fill inactive rows.

#define B_  8
#define S_  1024
#define D_  1024
#define H_  16
#define DH_ 64

using f16x8  = __attribute__((ext_vector_type(8))) _Float16;
using h16x2  = __attribute__((ext_vector_type(2))) __fp16;  // cvt_pkrtz result
using s16x8  = __attribute__((ext_vector_type(8))) short;
using f32x4  = __attribute__((ext_vector_type(4))) float;
using s16x4  = __attribute__((ext_vector_type(4))) short;

__device__ inline short f2h(float x) {
  _Float16 h = (_Float16)x;  // RNE
  return __builtin_bit_cast(short, h);
}

__device__ inline unsigned pk2(float a, float b) {  // 2 fp32 -> packed 2xfp16
  h16x2 p = __builtin_amdgcn_cvt_pkrtz(a, b);
  return __builtin_bit_cast(unsigned, p);
}

__device__ inline f16x8 ld_frag_g(const short* p) {  // 16B aligned
  return __builtin_bit_cast(f16x8, *(const s16x8*)p);
}

__device__ inline int kvlim_of(int vl, int ql) {  // effective k/v length
  const int v = (vl == 0) ? S_ : vl;
  return (v < ql) ? v : ql;
}

#define GLOAD_LDS16(gsrc, ldst)                                              \
  __builtin_amdgcn_global_load_lds(                                          \
      (const __attribute__((address_space(1))) unsigned int*)(gsrc),         \
      (__attribute__((address_space(3))) unsigned int*)(ldst), 16, 0, 0)

// -------------------------------------------------------------------- prep
// blocks 0..3071   : xcvt (8 tokens/block; regions beyond ceil128 of the
//                    effective length skipped -- never read downstream)
// blocks 3072..3839: wt_prep (Wt[slice][n][k] = W[k][n], 64x64 tiles)
// block  3840      : compaction lists (proj alist; attn alist2 qt-desc; zlist)
__global__ __launch_bounds__(256) void prep(
    const float* __restrict__ Qx, const float* __restrict__ Kx,
    const float* __restrict__ Vx, const float* __restrict__ WQ,
    const float* __restrict__ WK, const float* __restrict__ WV,
    short* __restrict__ dq, short* __restrict__ dk, short* __restrict__ dv,
    short* __restrict__ wt, int* __restrict__ alist, int* __restrict__ alist2,
    int* __restrict__ zlist, const int* __restrict__ Qlen,
    const int* __restrict__ Vlen) {
  __shared__ float t[64][65];
  __shared__ int scnt[257];
  const int bid = blockIdx.x;
  const int tid = threadIdx.x;
  if (bid == 3840) {  // ---- compaction
    int ql[8], kv[8];
#pragma unroll
    for (int b = 0; b < 8; ++b) {
      ql[b] = Qlen[b];
      kv[b] = kvlim_of(Vlen[b], ql[b]);
    }
    int loc[6];
    int cnt = 0;
#pragma unroll
    for (int k = 0; k < 6; ++k) {
      const int c = tid * 6 + k;
      const int slice = c % 3, r = c / 3;
      bool act;
      if (slice < 2) {
        const int jm = r & 63;
        const int m0 = (jm & 7) * 1024 + (jm >> 3) * 128;
        const int len = slice ? kv[m0 >> 10] : ql[m0 >> 10];
        act = (m0 & 1023) < len;
      } else {
        const int jn = r >> 3;
        const int n0 = (jn & 7) * 1024 + (jn >> 3) * 128;
        act = (n0 & 1023) < kv[n0 >> 10];
      }
      if (act) loc[cnt++] = c;
    }
    scnt[tid] = cnt;
    __syncthreads();
    if (tid == 0) {
      int s = 0;
      for (int i = 0; i < 256; ++i) {
        const int v = scnt[i];
        scnt[i] = s;
        s += v;
      }
      scnt[256] = s;
    }
    __syncthreads();
    const int base = scnt[tid];
    for (int k = 0; k < cnt; ++k) alist[base + k] = loc[k];
    if (tid == 0) {
      alist[1536] = scnt[256];
      // attn lists: qt-descending (heavy first), batch-minor
      int c2 = 0, zc = 0;
      for (int k = 0; k < 128; ++k) {
        const int qt = 15 - (k >> 3), b = k & 7;
        if (qt * 64 < ql[b])
          alist2[c2++] = (b << 4) | qt;
        else
          zlist[zc++] = (b << 4) | qt;
      }
      alist2[128] = c2;
      zlist[128] = zc;
    }
  } else if (bid < 3072) {
    const int slice = bid >> 10;
    const int tok0 = (bid & 1023) * 8;
    const int bb = tok0 >> 10, local = tok0 & 1023;
    const int ql = Qlen[bb];
    int lim;
    if (slice == 0) {
      lim = (ql + 127) & ~127;
    } else {
      lim = (kvlim_of(Vlen[bb], ql) + 127) & ~127;
    }
    if (local >= lim) return;  // region never read downstream
    const float* src = (slice == 0) ? Qx : (slice == 1) ? Kx : Vx;
    short* dst = (slice == 0) ? dq : (slice == 1) ? dk : dv;
    const size_t base = (size_t)(bid & 1023) * 8192;
#pragma unroll
    for (int j = 0; j < 4; ++j) {
      const size_t off = base + (size_t)j * 2048 + (size_t)tid * 8;
      float4 a = *(const float4*)(src + off);
      float4 b = *(const float4*)(src + off + 4);
      uint4 u = {pk2(a.x, a.y), pk2(a.z, a.w), pk2(b.x, b.y), pk2(b.z, b.w)};
      *(uint4*)(dst + off) = u;
    }
  } else {
    const int wid = bid - 3072;
    const int slice = wid >> 8;
    const int rem = wid & 255;
    const int n0 = (rem & 15) * 64, k0 = (rem >> 4) * 64;
    const float* W = (slice == 0) ? WQ : (slice == 1) ? WK : WV;
    {
      const int r = tid >> 2, c4 = tid & 3;
#pragma unroll
      for (int j = 0; j < 4; ++j) {
        float4 v = *(const float4*)(W + (size_t)(k0 + r) * D_ + n0 + c4 * 16 +
                                    j * 4);
        t[r][c4 * 16 + j * 4 + 0] = v.x;
        t[r][c4 * 16 + j * 4 + 1] = v.y;
        t[r][c4 * 16 + j * 4 + 2] = v.z;
        t[r][c4 * 16 + j * 4 + 3] = v.w;
      }
    }
    __syncthreads();
    {
      const int rn = tid >> 2, ks = tid & 3;
      short* dst =
          wt + ((size_t)slice << 20) + (size_t)(n0 + rn) * D_ + k0 + ks * 16;
      s16x4 h[4];
#pragma unroll
      for (int g = 0; g < 4; ++g)
#pragma unroll
        for (int j = 0; j < 4; ++j) h[g][j] = f2h(t[ks * 16 + g * 4 + j][rn]);
      *(s16x4*)(dst + 0) = h[0];
      *(s16x4*)(dst + 4) = h[1];
      *(s16x4*)(dst + 8) = h[2];
      *(s16x4*)(dst + 12) = h[3];
    }
  }
}

// ---------------------------------------------------------------- projections
// 1536 launched blocks; blocks >= alist[1536] exit; the rest read their tile
// from the compacted list (all active -> CUs packed 3-deep).
__global__ __launch_bounds__(256, 3) void proj(
    const short* __restrict__ xq, const short* __restrict__ xk,
    const short* __restrict__ xv, const short* __restrict__ wt,
    short* __restrict__ qp, short* __restrict__ kp, short* __restrict__ vp,
    const int* __restrict__ alist) {
  __shared__ __align__(16) short As[3][128][32];
  __shared__ __align__(16) short Bs[3][128][32];
  const int gid = blockIdx.x;
  if (gid >= alist[1536]) return;
  const int c = alist[gid];
  const int slice = c % 3;
  const int r = c / 3;
  const int tid = threadIdx.x;
  const short* A;
  const short* Bp;
  int m0, n0;
  float oscale;
  if (slice < 2) {
    A = slice ? xk : xq;              // rows = tokens (8192)
    Bp = wt + ((size_t)slice << 20);  // rows = H*Dh (1024)
    const int jm = r & 63;            // batch = jm&7 (fast), offset = jm>>3
    m0 = (jm & 7) * 1024 + (jm >> 3) * 128;
    n0 = (r >> 6) * 128;              // n-slow: 64 blocks share one Wt slab
    oscale = slice ? 1.0f : 0.125f;
  } else {
    A = wt + ((size_t)2 << 20);  // rows = H*Dh
    Bp = xv;                     // rows = tokens (8192)
    m0 = (r & 7) * 128;          // m-fast: 8 blocks share one X token band
    const int jn = r >> 3;       // batch = jn&7 (fast), offset = jn>>3
    n0 = (jn & 7) * 1024 + (jn >> 3) * 128;
    oscale = 1.0f;
  }

  const int lane = tid & 63, w = tid >> 6;
  const int wr = w >> 1, wc = w & 1;
  const int lr = lane & 15, lg = lane >> 4;
  const int g_row = tid >> 2, g_c = tid & 3;
  const int gsw = (g_c ^ ((g_row >> 1) & 3)) * 8;  // swizzled src granule
  const int rsw = (lg ^ ((lr >> 1) & 3)) * 8;      // swizzled read granule

  const short* ga = A + (size_t)(m0 + g_row) * D_ + gsw;
  const short* gb = Bp + (size_t)(n0 + g_row) * D_ + gsw;

  f32x4 acc[4][4];
#pragma unroll
  for (int i = 0; i < 4; ++i)
#pragma unroll
    for (int j = 0; j < 4; ++j) acc[i][j] = f32x4{0.f, 0.f, 0.f, 0.f};

  // prologue: stage buf0 (kt=0) and buf1 (kt=1); 8 loads outstanding
  GLOAD_LDS16(ga, &As[0][g_row][g_c * 8]);
  GLOAD_LDS16(ga + (size_t)64 * D_, &As[0][g_row + 64][g_c * 8]);
  GLOAD_LDS16(gb, &Bs[0][g_row][g_c * 8]);
  GLOAD_LDS16(gb + (size_t)64 * D_, &Bs[0][g_row + 64][g_c * 8]);
  GLOAD_LDS16(ga + 32, &As[1][g_row][g_c * 8]);
  GLOAD_LDS16(ga + (size_t)64 * D_ + 32, &As[1][g_row + 64][g_c * 8]);
  GLOAD_LDS16(gb + 32, &Bs[1][g_row][g_c * 8]);
  GLOAD_LDS16(gb + (size_t)64 * D_ + 32, &Bs[1][g_row + 64][g_c * 8]);

  for (int kt = 0; kt < 32; ++kt) {
    const int cur = kt % 3;
    if (kt < 30)
      asm volatile("s_waitcnt vmcnt(4)" ::: "memory");
    else
      asm volatile("s_waitcnt vmcnt(0)" ::: "memory");
    __builtin_amdgcn_s_barrier();
    __builtin_amdgcn_sched_barrier(0);
    if (kt < 30) {
      const int pre = (kt + 2) % 3;
      const int k2 = (kt + 2) * 32;
      GLOAD_LDS16(ga + k2, &As[pre][g_row][g_c * 8]);
      GLOAD_LDS16(ga + (size_t)64 * D_ + k2, &As[pre][g_row + 64][g_c * 8]);
      GLOAD_LDS16(gb + k2, &Bs[pre][g_row][g_c * 8]);
      GLOAD_LDS16(gb + (size_t)64 * D_ + k2, &Bs[pre][g_row + 64][g_c * 8]);
    }

    f16x8 af[4], bf[4];
#pragma unroll
    for (int mi = 0; mi < 4; ++mi)
      af[mi] = ld_frag_g(&As[cur][wr * 64 + mi * 16 + lr][rsw]);
#pragma unroll
    for (int ni = 0; ni < 4; ++ni)
      bf[ni] = ld_frag_g(&Bs[cur][wc * 64 + ni * 16 + lr][rsw]);
#pragma unroll
    for (int mi = 0; mi < 4; ++mi)
#pragma unroll
      for (int ni = 0; ni < 4; ++ni)
        acc[mi][ni] = __builtin_amdgcn_mfma_f32_16x16x32_f16(
            af[mi], bf[ni], acc[mi][ni], 0, 0, 0);
  }

  // epilogue
  short* outp = (slice == 0) ? qp : kp;
#pragma unroll
  for (int mi = 0; mi < 4; ++mi)
#pragma unroll
    for (int ni = 0; ni < 4; ++ni) {
      const int mg0 = m0 + wr * 64 + mi * 16 + lg * 4;
      const int ng = n0 + wc * 64 + ni * 16 + lr;
#pragma unroll
      for (int reg = 0; reg < 4; ++reg) {
        const int m = mg0 + reg;
        const short val = f2h(acc[mi][ni][reg] * oscale);
        if (slice < 2) {
          const int b = m >> 10, s = m & 1023, hh = ng >> 6, dh = ng & 63;
          outp[((size_t)((b * H_ + hh) * S_) + s) * DH_ + dh] = val;
        } else {
          vp[((size_t)(ng >> 10) << 20) + (size_t)m * S_ + (ng & 1023)] = val;
        }
      }
    }
}

// ----------------------------------------------------------------- attention
// Compacted: block g < 16*cnt2 computes q-tile (b,qt)=alist2[g>>4], head g&15
// (entries qt-descending -> heavy blocks dispatch first). Blocks after that
// zero-fill the 64 output rows of each inactive (b,qt) (4 blocks x 16 rows).
// Single q-tile, 4 waves x 16 rows; kf double-buffer + early vf loads.
// Shift-free softmax; masks only on last tile / vlen boundary.
__global__ __launch_bounds__(256, 3) void attn_fwd(
    const short* __restrict__ qp, const short* __restrict__ kp,
    const short* __restrict__ vT, const int* __restrict__ Qlen,
    const int* __restrict__ Vlen, float* __restrict__ out,
    const int* __restrict__ alist2, const int* __restrict__ zlist) {
  __shared__ short Plds[4][16][72];
  const int g = blockIdx.x;
  const int cnt2 = alist2[128];
  const int tid = threadIdx.x;
  if (g >= 16 * cnt2) {  // ---- zero-fill path (inactive q-tiles' out rows)
    const int zg = g - 16 * cnt2;
    if (zg >= 4 * zlist[128]) return;
    const int e = zlist[zg >> 2];
    const int b = e >> 4, qt = e & 15;
    const int row0 = qt * 64 + (zg & 3) * 16;
    float* ob = out + (size_t)(b * S_ + row0) * D_;
    const float4 zf = {0.f, 0.f, 0.f, 0.f};
#pragma unroll
    for (int i = 0; i < 16; ++i)
      *(float4*)(ob + (size_t)(i * 256 + tid) * 4) = zf;
    return;
  }
  const int e = alist2[g >> 4];
  const int h = g & 15;
  const int b = e >> 4, qt = e & 15;
  const int lane = tid & 63;
  const int w = tid >> 6;
  const int lr = lane & 15, lg = lane >> 4;
  const short* qb = qp + (size_t)((b * H_ + h) * S_) * DH_;
  const short* kb = kp + (size_t)((b * H_ + h) * S_) * DH_;
  const short* vb = vT + (size_t)((b * H_ + h) * DH_) * S_;
  const int vlen = Vlen[b], qlen = Qlen[b];
  const int vcap = (vlen + 63) >> 6;
  const int nT = (vlen > 0) ? min(qt + 1, vcap) : (qt + 1);
  const int q0 = qt * 64 + w * 16;

  f16x8 qf[2];
#pragma unroll
  for (int c = 0; c < 2; ++c)
    qf[c] = ld_frag_g(qb + (size_t)(q0 + lr) * DH_ + c * 32 + lg * 8);

  float l[4];
  f32x4 o[4];
#pragma unroll
  for (int rr = 0; rr < 4; ++rr) {
    l[rr] = 0.f;
    o[rr] = f32x4{0.f, 0.f, 0.f, 0.f};
  }

  f16x8 kf[8];
#pragma unroll
  for (int nt = 0; nt < 4; ++nt)
#pragma unroll
    for (int c = 0; c < 2; ++c)
      kf[nt * 2 + c] =
          ld_frag_g(kb + (size_t)(nt * 16 + lr) * DH_ + c * 32 + lg * 8);

  for (int t = 0; t < nT; ++t) {
    const int kv0 = t * 64;
    const int kvn = (t + 1 < nT) ? kv0 + 64 : kv0;

    f16x8 vf[8];
#pragma unroll
    for (int dt = 0; dt < 4; ++dt)
#pragma unroll
      for (int c = 0; c < 2; ++c)
        vf[dt * 2 + c] =
            ld_frag_g(vb + (size_t)(dt * 16 + lr) * S_ + kv0 + c * 32 + lg * 8);

    f16x8 kn[8];
#pragma unroll
    for (int nt = 0; nt < 4; ++nt)
#pragma unroll
      for (int c = 0; c < 2; ++c)
        kn[nt * 2 + c] = ld_frag_g(kb + (size_t)(kvn + nt * 16 + lr) * DH_ +
                                   c * 32 + lg * 8);

    f32x4 s[4];
#pragma unroll
    for (int nt = 0; nt < 4; ++nt) s[nt] = f32x4{0.f, 0.f, 0.f, 0.f};
#pragma unroll
    for (int nt = 0; nt < 4; ++nt)
#pragma unroll
      for (int c = 0; c < 2; ++c)
        s[nt] = __builtin_amdgcn_mfma_f32_16x16x32_f16(qf[c], kf[nt * 2 + c],
                                                       s[nt], 0, 0, 0);

    const bool km = (vlen > 0) && (vlen - kv0 < 64);
    if ((t == qt) | km) {
#pragma unroll
      for (int reg = 0; reg < 4; ++reg) {
        const int qrow = q0 + lg * 4 + reg;
#pragma unroll
        for (int nt = 0; nt < 4; ++nt) {
          const int kv = kv0 + nt * 16 + lr;
          float sv = s[nt][reg];
          if (km && kv >= vlen) sv -= 1e12f;
          if (kv > qrow) sv -= 1e12f;
          const float p = __expf(sv);
          l[reg] += p;
          Plds[w][lg * 4 + reg][nt * 16 + lr] = f2h(p);
        }
      }
    } else {
#pragma unroll
      for (int reg = 0; reg < 4; ++reg)
#pragma unroll
        for (int nt = 0; nt < 4; ++nt) {
          const float p = __expf(s[nt][reg]);
          l[reg] += p;
          Plds[w][lg * 4 + reg][nt * 16 + lr] = f2h(p);
        }
    }

#pragma unroll
    for (int c = 0; c < 2; ++c) {
      s16x4 a0 = *(const s16x4*)(&Plds[w][lr][c * 32 + lg * 8]);
      s16x4 a1 = *(const s16x4*)(&Plds[w][lr][c * 32 + lg * 8 + 4]);
      s16x8 pr = {a0[0], a0[1], a0[2], a0[3], a1[0], a1[1], a1[2], a1[3]};
      f16x8 pa = __builtin_bit_cast(f16x8, pr);
#pragma unroll
      for (int dt = 0; dt < 4; ++dt)
        o[dt] = __builtin_amdgcn_mfma_f32_16x16x32_f16(pa, vf[dt * 2 + c],
                                                       o[dt], 0, 0, 0);
    }

#pragma unroll
    for (int i = 0; i < 8; ++i) kf[i] = kn[i];
  }

#pragma unroll
  for (int reg = 0; reg < 4; ++reg) {
    float ls = l[reg];
    ls += __shfl_xor(ls, 1);
    ls += __shfl_xor(ls, 2);
    ls += __shfl_xor(ls, 4);
    ls += __shfl_xor(ls, 8);
    const int qrow = q0 + lg * 4 + reg;
    const float sc = (qrow < qlen) ? (1.f / ls) : 0.f;
#pragma unroll
    for (int dt = 0; dt < 4; ++dt)
      out[(size_t)(b * S_ + qrow) * D_ + h * DH_ + dt * 16 + lr] =
          o[dt][reg] * sc;
  }
}

// ------------------------------------------------------------------- launch
extern "C" void kernel_launch(void* const* d_in, const int* in_sizes, int n_in,
                              void* d_out, int out_size, void* d_ws,
                              size_t ws_size, hipStream_t stream) {
  const float* Q = (const float*)d_in[0];
  const float* K = (const float*)d_in[1];
  const float* V = (const float*)d_in[2];
  const float* WQ = (const float*)d_in[3];
  const float* WK = (const float*)d_in[4];
  const float* WV = (const float*)d_in[5];
  const int* Qlen = (const int*)d_in[6];
  const int* Vlen = (const int*)d_in[7];
  float* out = (float*)d_out;

  const size_t PE = (size_t)B_ * H_ * S_ * DH_;  // 8388608 elements
  short* qp = (short*)d_ws;
  short* kp = qp + PE;
  short* vT = kp + PE;
  short* wt = vT + PE;            // 3 x 1M fp16 = 6MB
  short* xhV = wt + 3 * 1048576;  // 16MB
  int* alist = (int*)(xhV + PE);  // 1537 ints
  int* alist2 = alist + 1540;     // 129 ints
  int* zlist = alist2 + 132;      // 129 ints (ws total ~70MB)
  // Q/K fp16 scratch lives in d_out (33.5MB >= 32MB); attn_fwd fully
  // overwrites d_out afterwards, so this is deterministic & safe.
  short* xhQ = (short*)d_out;
  short* xhK = xhQ + PE;

  prep<<<dim3(3841), dim3(256), 0, stream>>>(Q, K, V, WQ, WK, WV, xhQ, xhK,
                                             xhV, wt, alist, alist2, zlist,
                                             Qlen, Vlen);
  proj<<<dim3(1536), dim3(256), 0, stream>>>(xhQ, xhK, xhV, wt, qp, kp, vT,
                                             alist);
  attn_fwd<<<dim3(2560), dim3(256), 0, stream>>>(qp, kp, vT, Qlen, Vlen, out,
                                                 alist2, zlist);
}

// Round 22
// 103.368 us; speedup vs baseline: 1.1535x; 1.1535x over previous
//
#include <hip/hip_runtime.h>
#include <hip/hip_bf16.h>

// SelfAttention: O = softmax(mask((X_q WQ)(X_k WK)^T/8)) (X_v WV), causal +
// key-padding (V_len) + query (Q_len) masks. B=8 S=1024 D=1024 H=16 Dh=64.
//
// All intermediates FP16. Length-aware work skipping + ACTIVE-TILE COMPACTION:
//   - prep builds a compact list of active proj tiles (device-side, one
//     block, deterministic prefix-scan) so proj's executing blocks are ALL
//     active and pack the CUs 3-deep.
//   - q rows beyond ceil128(Q_len) are zero-filled by prep (attn reads q
//     unconditionally); k/v tiles beyond min(V_len?:S, Q_len) are simply
//     never computed (attn provably never reads them).
//   - attn halves whose q-tile is fully >= qlen skip all compute.
// Pipeline:
//   prep    : X fp32->fp16 + q zero-fill + Wt transpose + tile compaction.
//   proj    : compacted blocks; 128^2 tile, BK=32; both operands via
//             global_load_lds w16 into THREE rotating LDS buffers; counted
//             s_waitcnt vmcnt(4) + raw s_barrier; XOR-granule swizzle.
//   attn_fwd: flash attention, shift-free softmax, vlen tile skipping, fused
//             q-tile pairs {15-z, z} per block.

#define B_  8
#define S_  1024
#define D_  1024
#define H_  16
#define DH_ 64

using f16x8  = __attribute__((ext_vector_type(8))) _Float16;
using h16x2  = __attribute__((ext_vector_type(2))) __fp16;  // cvt_pkrtz result
using s16x8  = __attribute__((ext_vector_type(8))) short;
using f32x4  = __attribute__((ext_vector_type(4))) float;
using s16x4  = __attribute__((ext_vector_type(4))) short;

__device__ inline short f2h(float x) {
  _Float16 h = (_Float16)x;  // RNE
  return __builtin_bit_cast(short, h);
}

__device__ inline unsigned pk2(float a, float b) {  // 2 fp32 -> packed 2xfp16
  h16x2 p = __builtin_amdgcn_cvt_pkrtz(a, b);
  return __builtin_bit_cast(unsigned, p);
}

__device__ inline f16x8 ld_frag_g(const short* p) {  // 16B aligned
  return __builtin_bit_cast(f16x8, *(const s16x8*)p);
}

__device__ inline int kvlim_of(int vl, int ql) {  // effective k/v length
  const int v = (vl == 0) ? S_ : vl;
  return (v < ql) ? v : ql;
}

#define GLOAD_LDS16(gsrc, ldst)                                              \
  __builtin_amdgcn_global_load_lds(                                          \
      (const __attribute__((address_space(1))) unsigned int*)(gsrc),         \
      (__attribute__((address_space(3))) unsigned int*)(ldst), 16, 0, 0)

// -------------------------------------------------------------------- prep
// blocks 0..3071   : xcvt (slice = bid>>10, 8 tokens per block); skipped
//                    q regions zero-fill qp (attn reads q unconditionally),
//                    skipped k/v regions return (never read downstream).
// blocks 3072..3839: wt_prep (Wt[slice][n][k] = W[k][n], 64x64 tiles)
// block  3840      : active-tile compaction -> alist[0..cnt-1], alist[1536]=cnt
__global__ __launch_bounds__(256) void prep(
    const float* __restrict__ Qx, const float* __restrict__ Kx,
    const float* __restrict__ Vx, const float* __restrict__ WQ,
    const float* __restrict__ WK, const float* __restrict__ WV,
    short* __restrict__ dq, short* __restrict__ dk, short* __restrict__ dv,
    short* __restrict__ wt, short* __restrict__ qp, int* __restrict__ alist,
    const int* __restrict__ Qlen, const int* __restrict__ Vlen) {
  __shared__ float t[64][65];
  __shared__ int scnt[257];
  const int bid = blockIdx.x;
  const int tid = threadIdx.x;
  if (bid == 3840) {  // ---- compaction (candidate order == old gid order)
    int ql[8], kv[8];
#pragma unroll
    for (int b = 0; b < 8; ++b) {
      ql[b] = Qlen[b];
      kv[b] = kvlim_of(Vlen[b], ql[b]);
    }
    int loc[6];
    int cnt = 0;
#pragma unroll
    for (int k = 0; k < 6; ++k) {
      const int c = tid * 6 + k;
      const int slice = c % 3, r = c / 3;
      bool act;
      if (slice < 2) {
        const int jm = r & 63;
        const int m0 = (jm & 7) * 1024 + (jm >> 3) * 128;
        const int len = slice ? kv[m0 >> 10] : ql[m0 >> 10];
        act = (m0 & 1023) < len;
      } else {
        const int jn = r >> 3;
        const int n0 = (jn & 7) * 1024 + (jn >> 3) * 128;
        act = (n0 & 1023) < kv[n0 >> 10];
      }
      if (act) loc[cnt++] = c;
    }
    scnt[tid] = cnt;
    __syncthreads();
    if (tid == 0) {
      int s = 0;
      for (int i = 0; i < 256; ++i) {
        const int v = scnt[i];
        scnt[i] = s;
        s += v;
      }
      scnt[256] = s;
    }
    __syncthreads();
    const int base = scnt[tid];
    for (int k = 0; k < cnt; ++k) alist[base + k] = loc[k];
    if (tid == 0) alist[1536] = scnt[256];
  } else if (bid < 3072) {
    const int slice = bid >> 10;
    const int tok0 = (bid & 1023) * 8;
    const int bb = tok0 >> 10, local = tok0 & 1023;
    const int ql = Qlen[bb];
    int lim;
    if (slice == 0) {
      lim = (ql + 127) & ~127;
    } else {
      lim = (kvlim_of(Vlen[bb], ql) + 127) & ~127;
    }
    if (local >= lim) {
      if (slice == 0) {  // zero-fill qp rows for these 8 tokens, all heads
        const uint4 zz = {0u, 0u, 0u, 0u};
        const int hh = tid >> 4;
        short* zp = qp + ((size_t)((bb * H_ + hh) * S_) + local) * DH_ +
                    (tid & 15) * 32;
        *(uint4*)(zp + 0) = zz;
        *(uint4*)(zp + 8) = zz;
        *(uint4*)(zp + 16) = zz;
        *(uint4*)(zp + 24) = zz;
      }
      return;
    }
    const float* src = (slice == 0) ? Qx : (slice == 1) ? Kx : Vx;
    short* dst = (slice == 0) ? dq : (slice == 1) ? dk : dv;
    const size_t base = (size_t)(bid & 1023) * 8192;
#pragma unroll
    for (int j = 0; j < 4; ++j) {
      const size_t off = base + (size_t)j * 2048 + (size_t)tid * 8;
      float4 a = *(const float4*)(src + off);
      float4 b = *(const float4*)(src + off + 4);
      uint4 u = {pk2(a.x, a.y), pk2(a.z, a.w), pk2(b.x, b.y), pk2(b.z, b.w)};
      *(uint4*)(dst + off) = u;
    }
  } else {
    const int wid = bid - 3072;
    const int slice = wid >> 8;
    const int rem = wid & 255;
    const int n0 = (rem & 15) * 64, k0 = (rem >> 4) * 64;
    const float* W = (slice == 0) ? WQ : (slice == 1) ? WK : WV;
    {
      const int r = tid >> 2, c4 = tid & 3;
#pragma unroll
      for (int j = 0; j < 4; ++j) {
        float4 v = *(const float4*)(W + (size_t)(k0 + r) * D_ + n0 + c4 * 16 +
                                    j * 4);
        t[r][c4 * 16 + j * 4 + 0] = v.x;
        t[r][c4 * 16 + j * 4 + 1] = v.y;
        t[r][c4 * 16 + j * 4 + 2] = v.z;
        t[r][c4 * 16 + j * 4 + 3] = v.w;
      }
    }
    __syncthreads();
    {
      const int rn = tid >> 2, ks = tid & 3;
      short* dst =
          wt + ((size_t)slice << 20) + (size_t)(n0 + rn) * D_ + k0 + ks * 16;
      s16x4 h[4];
#pragma unroll
      for (int g = 0; g < 4; ++g)
#pragma unroll
        for (int j = 0; j < 4; ++j) h[g][j] = f2h(t[ks * 16 + g * 4 + j][rn]);
      *(s16x4*)(dst + 0) = h[0];
      *(s16x4*)(dst + 4) = h[1];
      *(s16x4*)(dst + 8) = h[2];
      *(s16x4*)(dst + 12) = h[3];
    }
  }
}

// ---------------------------------------------------------------- projections
// 1536 launched blocks; blocks >= alist[1536] exit; the rest read their tile
// from the compacted list (all active -> CUs packed 3-deep).
// 128x128 tile, BK=32; THREE rotating [128][32] buffers/operand; counted
// vmcnt(4) + raw s_barrier per step; XOR-granule swizzle (conflict-free).
__global__ __launch_bounds__(256, 3) void proj(
    const short* __restrict__ xq, const short* __restrict__ xk,
    const short* __restrict__ xv, const short* __restrict__ wt,
    short* __restrict__ qp, short* __restrict__ kp, short* __restrict__ vp,
    const int* __restrict__ alist) {
  __shared__ __align__(16) short As[3][128][32];
  __shared__ __align__(16) short Bs[3][128][32];
  const int gid = blockIdx.x;
  if (gid >= alist[1536]) return;
  const int c = alist[gid];
  const int slice = c % 3;
  const int r = c / 3;
  const int tid = threadIdx.x;
  const short* A;
  const short* Bp;
  int m0, n0;
  float oscale;
  if (slice < 2) {
    A = slice ? xk : xq;              // rows = tokens (8192)
    Bp = wt + ((size_t)slice << 20);  // rows = H*Dh (1024)
    const int jm = r & 63;            // batch = jm&7 (fast), offset = jm>>3
    m0 = (jm & 7) * 1024 + (jm >> 3) * 128;
    n0 = (r >> 6) * 128;              // n-slow: 64 blocks share one Wt slab
    oscale = slice ? 1.0f : 0.125f;
  } else {
    A = wt + ((size_t)2 << 20);  // rows = H*Dh
    Bp = xv;                     // rows = tokens (8192)
    m0 = (r & 7) * 128;          // m-fast: 8 blocks share one X token band
    const int jn = r >> 3;       // batch = jn&7 (fast), offset = jn>>3
    n0 = (jn & 7) * 1024 + (jn >> 3) * 128;
    oscale = 1.0f;
  }

  const int lane = tid & 63, w = tid >> 6;
  const int wr = w >> 1, wc = w & 1;
  const int lr = lane & 15, lg = lane >> 4;
  const int g_row = tid >> 2, g_c = tid & 3;
  const int gsw = (g_c ^ ((g_row >> 1) & 3)) * 8;  // swizzled src granule
  const int rsw = (lg ^ ((lr >> 1) & 3)) * 8;      // swizzled read granule

  const short* ga = A + (size_t)(m0 + g_row) * D_ + gsw;
  const short* gb = Bp + (size_t)(n0 + g_row) * D_ + gsw;

  f32x4 acc[4][4];
#pragma unroll
  for (int i = 0; i < 4; ++i)
#pragma unroll
    for (int j = 0; j < 4; ++j) acc[i][j] = f32x4{0.f, 0.f, 0.f, 0.f};

  // prologue: stage buf0 (kt=0) and buf1 (kt=1); 8 loads outstanding
  GLOAD_LDS16(ga, &As[0][g_row][g_c * 8]);
  GLOAD_LDS16(ga + (size_t)64 * D_, &As[0][g_row + 64][g_c * 8]);
  GLOAD_LDS16(gb, &Bs[0][g_row][g_c * 8]);
  GLOAD_LDS16(gb + (size_t)64 * D_, &Bs[0][g_row + 64][g_c * 8]);
  GLOAD_LDS16(ga + 32, &As[1][g_row][g_c * 8]);
  GLOAD_LDS16(ga + (size_t)64 * D_ + 32, &As[1][g_row + 64][g_c * 8]);
  GLOAD_LDS16(gb + 32, &Bs[1][g_row][g_c * 8]);
  GLOAD_LDS16(gb + (size_t)64 * D_ + 32, &Bs[1][g_row + 64][g_c * 8]);

  for (int kt = 0; kt < 32; ++kt) {
    const int cur = kt % 3;
    if (kt < 30)
      asm volatile("s_waitcnt vmcnt(4)" ::: "memory");
    else
      asm volatile("s_waitcnt vmcnt(0)" ::: "memory");
    __builtin_amdgcn_s_barrier();
    __builtin_amdgcn_sched_barrier(0);
    if (kt < 30) {
      const int pre = (kt + 2) % 3;
      const int k2 = (kt + 2) * 32;
      GLOAD_LDS16(ga + k2, &As[pre][g_row][g_c * 8]);
      GLOAD_LDS16(ga + (size_t)64 * D_ + k2, &As[pre][g_row + 64][g_c * 8]);
      GLOAD_LDS16(gb + k2, &Bs[pre][g_row][g_c * 8]);
      GLOAD_LDS16(gb + (size_t)64 * D_ + k2, &Bs[pre][g_row + 64][g_c * 8]);
    }

    f16x8 af[4], bf[4];
#pragma unroll
    for (int mi = 0; mi < 4; ++mi)
      af[mi] = ld_frag_g(&As[cur][wr * 64 + mi * 16 + lr][rsw]);
#pragma unroll
    for (int ni = 0; ni < 4; ++ni)
      bf[ni] = ld_frag_g(&Bs[cur][wc * 64 + ni * 16 + lr][rsw]);
#pragma unroll
    for (int mi = 0; mi < 4; ++mi)
#pragma unroll
      for (int ni = 0; ni < 4; ++ni)
        acc[mi][ni] = __builtin_amdgcn_mfma_f32_16x16x32_f16(
            af[mi], bf[ni], acc[mi][ni], 0, 0, 0);
  }

  // epilogue
  short* outp = (slice == 0) ? qp : kp;
#pragma unroll
  for (int mi = 0; mi < 4; ++mi)
#pragma unroll
    for (int ni = 0; ni < 4; ++ni) {
      const int mg0 = m0 + wr * 64 + mi * 16 + lg * 4;
      const int ng = n0 + wc * 64 + ni * 16 + lr;
#pragma unroll
      for (int reg = 0; reg < 4; ++reg) {
        const int m = mg0 + reg;
        const short val = f2h(acc[mi][ni][reg] * oscale);
        if (slice < 2) {
          const int b = m >> 10, s = m & 1023, hh = ng >> 6, dh = ng & 63;
          outp[((size_t)((b * H_ + hh) * S_) + s) * DH_ + dh] = val;
        } else {
          vp[((size_t)(ng >> 10) << 20) + (size_t)m * S_ + (ng & 1023)] = val;
        }
      }
    }
}

// ----------------------------------------------------------------- attention
// Block = (b, h, z): q-tiles {qtH=15-z, qtL=z}, ONE fused sweep over KV tiles.
// Halves whose q-tile lies fully >= qlen are inactive (sc=0 already zeroes
// their output rows); the KV loop runs to the max active bound only.
// Shift-free softmax (p = exp(s); exp(s - 1e12) == 0.0f exactly). Tiles with
// kv0 >= vlen skipped (vlen>0); vlen==0 degrades to plain causal softmax.
__global__ __launch_bounds__(256, 2) void attn_fwd(
    const short* __restrict__ qp, const short* __restrict__ kp,
    const short* __restrict__ vT, const int* __restrict__ Qlen,
    const int* __restrict__ Vlen, float* __restrict__ out) {
  __shared__ short Plds[2][4][16][72];
  const int bid = blockIdx.x;
  const int z = bid & 7;
  const int bh = bid >> 3;
  const int h = bh & 15;
  const int b = bh >> 4;
  const int lane = threadIdx.x & 63;
  const int w = threadIdx.x >> 6;
  const int lr = lane & 15, lg = lane >> 4;
  const short* qb = qp + (size_t)((b * H_ + h) * S_) * DH_;
  const short* kb = kp + (size_t)((b * H_ + h) * S_) * DH_;
  const short* vb = vT + (size_t)((b * H_ + h) * DH_) * S_;
  const int vlen = Vlen[b], qlen = Qlen[b];

  const int qtH = 15 - z, qtL = z;
  const int vcap = (vlen + 63) >> 6;
  const int nTH = (vlen > 0) ? min(qtH + 1, vcap) : (qtH + 1);
  const int nTL = (vlen > 0) ? min(qtL + 1, vcap) : (qtL + 1);
  const int q0H = qtH * 64 + w * 16;
  const int q0L = qtL * 64 + w * 16;

  const bool hAct = qlen > qtH * 64;  // any active q row in the H tile
  const bool lAct = qlen > qtL * 64;
  const int tHn = hAct ? nTH : 0;
  const int tLn = lAct ? nTL : 0;
  const int tMax = (tHn > tLn) ? tHn : tLn;

  f16x8 qfH[2], qfL[2];
#pragma unroll
  for (int c = 0; c < 2; ++c) {
    qfH[c] = ld_frag_g(qb + (size_t)(q0H + lr) * DH_ + c * 32 + lg * 8);
    qfL[c] = ld_frag_g(qb + (size_t)(q0L + lr) * DH_ + c * 32 + lg * 8);
  }

  float lH[4], lL[4];
  f32x4 oH[4], oL[4];
#pragma unroll
  for (int rr = 0; rr < 4; ++rr) {
    lH[rr] = 0.f; lL[rr] = 0.f;
    oH[rr] = f32x4{0.f, 0.f, 0.f, 0.f};
    oL[rr] = f32x4{0.f, 0.f, 0.f, 0.f};
  }

  f16x8 kf[8];
#pragma unroll
  for (int nt = 0; nt < 4; ++nt)
#pragma unroll
    for (int c = 0; c < 2; ++c)
      kf[nt * 2 + c] =
          ld_frag_g(kb + (size_t)(nt * 16 + lr) * DH_ + c * 32 + lg * 8);

  for (int t = 0; t < tMax; ++t) {
    const int kv0 = t * 64;
    const int kvn = (t + 1 < tMax) ? kv0 + 64 : kv0;
    const bool hact = t < tHn;
    const bool lact = t < tLn;

    f16x8 vf[8];
#pragma unroll
    for (int dt = 0; dt < 4; ++dt)
#pragma unroll
      for (int c = 0; c < 2; ++c)
        vf[dt * 2 + c] =
            ld_frag_g(vb + (size_t)(dt * 16 + lr) * S_ + kv0 + c * 32 + lg * 8);

    f16x8 kn[8];
#pragma unroll
    for (int nt = 0; nt < 4; ++nt)
#pragma unroll
      for (int c = 0; c < 2; ++c)
        kn[nt * 2 + c] = ld_frag_g(kb + (size_t)(kvn + nt * 16 + lr) * DH_ +
                                   c * 32 + lg * 8);

    const bool km = (vlen > 0) && (vlen - kv0 < 64);

    f32x4 sH[4], sL[4];
    if (hact) {
#pragma unroll
      for (int nt = 0; nt < 4; ++nt) sH[nt] = f32x4{0.f, 0.f, 0.f, 0.f};
#pragma unroll
      for (int nt = 0; nt < 4; ++nt)
#pragma unroll
        for (int c = 0; c < 2; ++c)
          sH[nt] = __builtin_amdgcn_mfma_f32_16x16x32_f16(
              qfH[c], kf[nt * 2 + c], sH[nt], 0, 0, 0);
    }
    if (lact) {
#pragma unroll
      for (int nt = 0; nt < 4; ++nt) sL[nt] = f32x4{0.f, 0.f, 0.f, 0.f};
#pragma unroll
      for (int nt = 0; nt < 4; ++nt)
#pragma unroll
        for (int c = 0; c < 2; ++c)
          sL[nt] = __builtin_amdgcn_mfma_f32_16x16x32_f16(
              qfL[c], kf[nt * 2 + c], sL[nt], 0, 0, 0);
    }

    if (hact) {
      if ((t == qtH) | km) {
#pragma unroll
        for (int reg = 0; reg < 4; ++reg) {
          const int qrow = q0H + lg * 4 + reg;
#pragma unroll
          for (int nt = 0; nt < 4; ++nt) {
            const int kv = kv0 + nt * 16 + lr;
            float sv = sH[nt][reg];
            if (km && kv >= vlen) sv -= 1e12f;
            if (kv > qrow) sv -= 1e12f;
            const float p = __expf(sv);
            lH[reg] += p;
            Plds[0][w][lg * 4 + reg][nt * 16 + lr] = f2h(p);
          }
        }
      } else {
#pragma unroll
        for (int reg = 0; reg < 4; ++reg)
#pragma unroll
          for (int nt = 0; nt < 4; ++nt) {
            const float p = __expf(sH[nt][reg]);
            lH[reg] += p;
            Plds[0][w][lg * 4 + reg][nt * 16 + lr] = f2h(p);
          }
      }
    }
    if (lact) {
      if ((t == qtL) | km) {
#pragma unroll
        for (int reg = 0; reg < 4; ++reg) {
          const int qrow = q0L + lg * 4 + reg;
#pragma unroll
          for (int nt = 0; nt < 4; ++nt) {
            const int kv = kv0 + nt * 16 + lr;
            float sv = sL[nt][reg];
            if (km && kv >= vlen) sv -= 1e12f;
            if (kv > qrow) sv -= 1e12f;
            const float p = __expf(sv);
            lL[reg] += p;
            Plds[1][w][lg * 4 + reg][nt * 16 + lr] = f2h(p);
          }
        }
      } else {
#pragma unroll
        for (int reg = 0; reg < 4; ++reg)
#pragma unroll
          for (int nt = 0; nt < 4; ++nt) {
            const float p = __expf(sL[nt][reg]);
            lL[reg] += p;
            Plds[1][w][lg * 4 + reg][nt * 16 + lr] = f2h(p);
          }
      }
    }

    if (hact) {
#pragma unroll
      for (int c = 0; c < 2; ++c) {
        s16x4 a0 = *(const s16x4*)(&Plds[0][w][lr][c * 32 + lg * 8]);
        s16x4 a1 = *(const s16x4*)(&Plds[0][w][lr][c * 32 + lg * 8 + 4]);
        s16x8 pr = {a0[0], a0[1], a0[2], a0[3], a1[0], a1[1], a1[2], a1[3]};
        f16x8 paH = __builtin_bit_cast(f16x8, pr);
#pragma unroll
        for (int dt = 0; dt < 4; ++dt)
          oH[dt] = __builtin_amdgcn_mfma_f32_16x16x32_f16(paH, vf[dt * 2 + c],
                                                          oH[dt], 0, 0, 0);
      }
    }
    if (lact) {
#pragma unroll
      for (int c = 0; c < 2; ++c) {
        s16x4 a0 = *(const s16x4*)(&Plds[1][w][lr][c * 32 + lg * 8]);
        s16x4 a1 = *(const s16x4*)(&Plds[1][w][lr][c * 32 + lg * 8 + 4]);
        s16x8 pr = {a0[0], a0[1], a0[2], a0[3], a1[0], a1[1], a1[2], a1[3]};
        f16x8 paL = __builtin_bit_cast(f16x8, pr);
#pragma unroll
        for (int dt = 0; dt < 4; ++dt)
          oL[dt] = __builtin_amdgcn_mfma_f32_16x16x32_f16(paL, vf[dt * 2 + c],
                                                          oL[dt], 0, 0, 0);
      }
    }

#pragma unroll
    for (int i = 0; i < 8; ++i) kf[i] = kn[i];
  }

#pragma unroll
  for (int reg = 0; reg < 4; ++reg) {
    float ls = lH[reg];
    ls += __shfl_xor(ls, 1);
    ls += __shfl_xor(ls, 2);
    ls += __shfl_xor(ls, 4);
    ls += __shfl_xor(ls, 8);
    const int qrow = q0H + lg * 4 + reg;
    const float sc = (qrow < qlen) ? (1.f / ls) : 0.f;
#pragma unroll
    for (int dt = 0; dt < 4; ++dt)
      out[(size_t)(b * S_ + qrow) * D_ + h * DH_ + dt * 16 + lr] =
          oH[dt][reg] * sc;
  }
#pragma unroll
  for (int reg = 0; reg < 4; ++reg) {
    float ls = lL[reg];
    ls += __shfl_xor(ls, 1);
    ls += __shfl_xor(ls, 2);
    ls += __shfl_xor(ls, 4);
    ls += __shfl_xor(ls, 8);
    const int qrow = q0L + lg * 4 + reg;
    const float sc = (qrow < qlen) ? (1.f / ls) : 0.f;
#pragma unroll
    for (int dt = 0; dt < 4; ++dt)
      out[(size_t)(b * S_ + qrow) * D_ + h * DH_ + dt * 16 + lr] =
          oL[dt][reg] * sc;
  }
}

// ------------------------------------------------------------------- launch
extern "C" void kernel_launch(void* const* d_in, const int* in_sizes, int n_in,
                              void* d_out, int out_size, void* d_ws,
                              size_t ws_size, hipStream_t stream) {
  const float* Q = (const float*)d_in[0];
  const float* K = (const float*)d_in[1];
  const float* V = (const float*)d_in[2];
  const float* WQ = (const float*)d_in[3];
  const float* WK = (const float*)d_in[4];
  const float* WV = (const float*)d_in[5];
  const int* Qlen = (const int*)d_in[6];
  const int* Vlen = (const int*)d_in[7];
  float* out = (float*)d_out;

  const size_t PE = (size_t)B_ * H_ * S_ * DH_;  // 8388608 elements
  short* qp = (short*)d_ws;
  short* kp = qp + PE;
  short* vT = kp + PE;
  short* wt = vT + PE;            // 3 x 1M fp16 = 6MB
  short* xhV = wt + 3 * 1048576;  // 16MB
  int* alist = (int*)(xhV + PE);  // 1537 ints (~6KB; ws total ~70MB)
  // Q/K fp16 scratch lives in d_out (33.5MB >= 32MB); attn_fwd fully
  // overwrites d_out afterwards, so this is deterministic & safe.
  short* xhQ = (short*)d_out;
  short* xhK = xhQ + PE;

  prep<<<dim3(3841), dim3(256), 0, stream>>>(Q, K, V, WQ, WK, WV, xhQ, xhK,
                                             xhV, wt, qp, alist, Qlen, Vlen);
  proj<<<dim3(1536), dim3(256), 0, stream>>>(xhQ, xhK, xhV, wt, qp, kp, vT,
                                             alist);
  attn_fwd<<<dim3(1024), dim3(256), 0, stream>>>(qp, kp, vT, Qlen, Vlen, out);
}

// Round 23
// 85.473 us; speedup vs baseline: 1.3950x; 1.2094x over previous
//
#include <hip/hip_runtime.h>
#include <hip/hip_bf16.h>

// SelfAttention: O = softmax(mask((X_q WQ)(X_k WK)^T/8)) (X_v WV), causal +
// key-padding (V_len) + query (Q_len) masks. B=8 S=1024 D=1024 H=16 Dh=64.
//
// All intermediates FP16. Length-aware skipping + proj tile compaction
// (R20 config) + attn K/V LDS staging (proj's proven skeleton: gload_lds w16
// into 3 rotating buffers, counted vmcnt(4) + raw s_barrier, XOR-granule
// swizzle on source+read) -- kills the 4x-redundant per-wave global K/V
// loads that made attn latency-bound (MfmaUtil 3%).

#define B_  8
#define S_  1024
#define D_  1024
#define H_  16
#define DH_ 64

using f16x8  = __attribute__((ext_vector_type(8))) _Float16;
using h16x2  = __attribute__((ext_vector_type(2))) __fp16;  // cvt_pkrtz result
using s16x8  = __attribute__((ext_vector_type(8))) short;
using f32x4  = __attribute__((ext_vector_type(4))) float;
using s16x4  = __attribute__((ext_vector_type(4))) short;

__device__ inline short f2h(float x) {
  _Float16 h = (_Float16)x;  // RNE
  return __builtin_bit_cast(short, h);
}

__device__ inline unsigned pk2(float a, float b) {  // 2 fp32 -> packed 2xfp16
  h16x2 p = __builtin_amdgcn_cvt_pkrtz(a, b);
  return __builtin_bit_cast(unsigned, p);
}

__device__ inline f16x8 ld_frag_g(const short* p) {  // 16B aligned
  return __builtin_bit_cast(f16x8, *(const s16x8*)p);
}

__device__ inline int kvlim_of(int vl, int ql) {  // effective k/v length
  const int v = (vl == 0) ? S_ : vl;
  return (v < ql) ? v : ql;
}

#define GLOAD_LDS16(gsrc, ldst)                                              \
  __builtin_amdgcn_global_load_lds(                                          \
      (const __attribute__((address_space(1))) unsigned int*)(gsrc),         \
      (__attribute__((address_space(3))) unsigned int*)(ldst), 16, 0, 0)

// -------------------------------------------------------------------- prep
// blocks 0..3071   : xcvt (slice = bid>>10, 8 tokens per block); skipped
//                    q regions zero-fill qp (attn reads q unconditionally),
//                    skipped k/v regions return (never read downstream).
// blocks 3072..3839: wt_prep (Wt[slice][n][k] = W[k][n], 64x64 tiles)
// block  3840      : active-tile compaction -> alist[0..cnt-1], alist[1536]=cnt
__global__ __launch_bounds__(256) void prep(
    const float* __restrict__ Qx, const float* __restrict__ Kx,
    const float* __restrict__ Vx, const float* __restrict__ WQ,
    const float* __restrict__ WK, const float* __restrict__ WV,
    short* __restrict__ dq, short* __restrict__ dk, short* __restrict__ dv,
    short* __restrict__ wt, short* __restrict__ qp, int* __restrict__ alist,
    const int* __restrict__ Qlen, const int* __restrict__ Vlen) {
  __shared__ float t[64][65];
  __shared__ int scnt[257];
  const int bid = blockIdx.x;
  const int tid = threadIdx.x;
  if (bid == 3840) {  // ---- compaction (candidate order == old gid order)
    int ql[8], kv[8];
#pragma unroll
    for (int b = 0; b < 8; ++b) {
      ql[b] = Qlen[b];
      kv[b] = kvlim_of(Vlen[b], ql[b]);
    }
    int loc[6];
    int cnt = 0;
#pragma unroll
    for (int k = 0; k < 6; ++k) {
      const int c = tid * 6 + k;
      const int slice = c % 3, r = c / 3;
      bool act;
      if (slice < 2) {
        const int jm = r & 63;
        const int m0 = (jm & 7) * 1024 + (jm >> 3) * 128;
        const int len = slice ? kv[m0 >> 10] : ql[m0 >> 10];
        act = (m0 & 1023) < len;
      } else {
        const int jn = r >> 3;
        const int n0 = (jn & 7) * 1024 + (jn >> 3) * 128;
        act = (n0 & 1023) < kv[n0 >> 10];
      }
      if (act) loc[cnt++] = c;
    }
    scnt[tid] = cnt;
    __syncthreads();
    if (tid == 0) {
      int s = 0;
      for (int i = 0; i < 256; ++i) {
        const int v = scnt[i];
        scnt[i] = s;
        s += v;
      }
      scnt[256] = s;
    }
    __syncthreads();
    const int base = scnt[tid];
    for (int k = 0; k < cnt; ++k) alist[base + k] = loc[k];
    if (tid == 0) alist[1536] = scnt[256];
  } else if (bid < 3072) {
    const int slice = bid >> 10;
    const int tok0 = (bid & 1023) * 8;
    const int bb = tok0 >> 10, local = tok0 & 1023;
    const int ql = Qlen[bb];
    int lim;
    if (slice == 0) {
      lim = (ql + 127) & ~127;
    } else {
      lim = (kvlim_of(Vlen[bb], ql) + 127) & ~127;
    }
    if (local >= lim) {
      if (slice == 0) {  // zero-fill qp rows for these 8 tokens, all heads
        const uint4 zz = {0u, 0u, 0u, 0u};
        const int hh = tid >> 4;
        short* zp = qp + ((size_t)((bb * H_ + hh) * S_) + local) * DH_ +
                    (tid & 15) * 32;
        *(uint4*)(zp + 0) = zz;
        *(uint4*)(zp + 8) = zz;
        *(uint4*)(zp + 16) = zz;
        *(uint4*)(zp + 24) = zz;
      }
      return;
    }
    const float* src = (slice == 0) ? Qx : (slice == 1) ? Kx : Vx;
    short* dst = (slice == 0) ? dq : (slice == 1) ? dk : dv;
    const size_t base = (size_t)(bid & 1023) * 8192;
#pragma unroll
    for (int j = 0; j < 4; ++j) {
      const size_t off = base + (size_t)j * 2048 + (size_t)tid * 8;
      float4 a = *(const float4*)(src + off);
      float4 b = *(const float4*)(src + off + 4);
      uint4 u = {pk2(a.x, a.y), pk2(a.z, a.w), pk2(b.x, b.y), pk2(b.z, b.w)};
      *(uint4*)(dst + off) = u;
    }
  } else {
    const int wid = bid - 3072;
    const int slice = wid >> 8;
    const int rem = wid & 255;
    const int n0 = (rem & 15) * 64, k0 = (rem >> 4) * 64;
    const float* W = (slice == 0) ? WQ : (slice == 1) ? WK : WV;
    {
      const int r = tid >> 2, c4 = tid & 3;
#pragma unroll
      for (int j = 0; j < 4; ++j) {
        float4 v = *(const float4*)(W + (size_t)(k0 + r) * D_ + n0 + c4 * 16 +
                                    j * 4);
        t[r][c4 * 16 + j * 4 + 0] = v.x;
        t[r][c4 * 16 + j * 4 + 1] = v.y;
        t[r][c4 * 16 + j * 4 + 2] = v.z;
        t[r][c4 * 16 + j * 4 + 3] = v.w;
      }
    }
    __syncthreads();
    {
      const int rn = tid >> 2, ks = tid & 3;
      short* dst =
          wt + ((size_t)slice << 20) + (size_t)(n0 + rn) * D_ + k0 + ks * 16;
      s16x4 h[4];
#pragma unroll
      for (int g = 0; g < 4; ++g)
#pragma unroll
        for (int j = 0; j < 4; ++j) h[g][j] = f2h(t[ks * 16 + g * 4 + j][rn]);
      *(s16x4*)(dst + 0) = h[0];
      *(s16x4*)(dst + 4) = h[1];
      *(s16x4*)(dst + 8) = h[2];
      *(s16x4*)(dst + 12) = h[3];
    }
  }
}

// ---------------------------------------------------------------- projections
// 1536 launched blocks; blocks >= alist[1536] exit; the rest read their tile
// from the compacted list (all active -> CUs packed 3-deep).
__global__ __launch_bounds__(256, 3) void proj(
    const short* __restrict__ xq, const short* __restrict__ xk,
    const short* __restrict__ xv, const short* __restrict__ wt,
    short* __restrict__ qp, short* __restrict__ kp, short* __restrict__ vp,
    const int* __restrict__ alist) {
  __shared__ __align__(16) short As[3][128][32];
  __shared__ __align__(16) short Bs[3][128][32];
  const int gid = blockIdx.x;
  if (gid >= alist[1536]) return;
  const int c = alist[gid];
  const int slice = c % 3;
  const int r = c / 3;
  const int tid = threadIdx.x;
  const short* A;
  const short* Bp;
  int m0, n0;
  float oscale;
  if (slice < 2) {
    A = slice ? xk : xq;              // rows = tokens (8192)
    Bp = wt + ((size_t)slice << 20);  // rows = H*Dh (1024)
    const int jm = r & 63;            // batch = jm&7 (fast), offset = jm>>3
    m0 = (jm & 7) * 1024 + (jm >> 3) * 128;
    n0 = (r >> 6) * 128;              // n-slow: 64 blocks share one Wt slab
    oscale = slice ? 1.0f : 0.125f;
  } else {
    A = wt + ((size_t)2 << 20);  // rows = H*Dh
    Bp = xv;                     // rows = tokens (8192)
    m0 = (r & 7) * 128;          // m-fast: 8 blocks share one X token band
    const int jn = r >> 3;       // batch = jn&7 (fast), offset = jn>>3
    n0 = (jn & 7) * 1024 + (jn >> 3) * 128;
    oscale = 1.0f;
  }

  const int lane = tid & 63, w = tid >> 6;
  const int wr = w >> 1, wc = w & 1;
  const int lr = lane & 15, lg = lane >> 4;
  const int g_row = tid >> 2, g_c = tid & 3;
  const int gsw = (g_c ^ ((g_row >> 1) & 3)) * 8;  // swizzled src granule
  const int rsw = (lg ^ ((lr >> 1) & 3)) * 8;      // swizzled read granule

  const short* ga = A + (size_t)(m0 + g_row) * D_ + gsw;
  const short* gb = Bp + (size_t)(n0 + g_row) * D_ + gsw;

  f32x4 acc[4][4];
#pragma unroll
  for (int i = 0; i < 4; ++i)
#pragma unroll
    for (int j = 0; j < 4; ++j) acc[i][j] = f32x4{0.f, 0.f, 0.f, 0.f};

  // prologue: stage buf0 (kt=0) and buf1 (kt=1); 8 loads outstanding
  GLOAD_LDS16(ga, &As[0][g_row][g_c * 8]);
  GLOAD_LDS16(ga + (size_t)64 * D_, &As[0][g_row + 64][g_c * 8]);
  GLOAD_LDS16(gb, &Bs[0][g_row][g_c * 8]);
  GLOAD_LDS16(gb + (size_t)64 * D_, &Bs[0][g_row + 64][g_c * 8]);
  GLOAD_LDS16(ga + 32, &As[1][g_row][g_c * 8]);
  GLOAD_LDS16(ga + (size_t)64 * D_ + 32, &As[1][g_row + 64][g_c * 8]);
  GLOAD_LDS16(gb + 32, &Bs[1][g_row][g_c * 8]);
  GLOAD_LDS16(gb + (size_t)64 * D_ + 32, &Bs[1][g_row + 64][g_c * 8]);

  for (int kt = 0; kt < 32; ++kt) {
    const int cur = kt % 3;
    if (kt < 30)
      asm volatile("s_waitcnt vmcnt(4)" ::: "memory");
    else
      asm volatile("s_waitcnt vmcnt(0)" ::: "memory");
    __builtin_amdgcn_s_barrier();
    __builtin_amdgcn_sched_barrier(0);
    if (kt < 30) {
      const int pre = (kt + 2) % 3;
      const int k2 = (kt + 2) * 32;
      GLOAD_LDS16(ga + k2, &As[pre][g_row][g_c * 8]);
      GLOAD_LDS16(ga + (size_t)64 * D_ + k2, &As[pre][g_row + 64][g_c * 8]);
      GLOAD_LDS16(gb + k2, &Bs[pre][g_row][g_c * 8]);
      GLOAD_LDS16(gb + (size_t)64 * D_ + k2, &Bs[pre][g_row + 64][g_c * 8]);
    }

    f16x8 af[4], bf[4];
#pragma unroll
    for (int mi = 0; mi < 4; ++mi)
      af[mi] = ld_frag_g(&As[cur][wr * 64 + mi * 16 + lr][rsw]);
#pragma unroll
    for (int ni = 0; ni < 4; ++ni)
      bf[ni] = ld_frag_g(&Bs[cur][wc * 64 + ni * 16 + lr][rsw]);
#pragma unroll
    for (int mi = 0; mi < 4; ++mi)
#pragma unroll
      for (int ni = 0; ni < 4; ++ni)
        acc[mi][ni] = __builtin_amdgcn_mfma_f32_16x16x32_f16(
            af[mi], bf[ni], acc[mi][ni], 0, 0, 0);
  }

  // epilogue
  short* outp = (slice == 0) ? qp : kp;
#pragma unroll
  for (int mi = 0; mi < 4; ++mi)
#pragma unroll
    for (int ni = 0; ni < 4; ++ni) {
      const int mg0 = m0 + wr * 64 + mi * 16 + lg * 4;
      const int ng = n0 + wc * 64 + ni * 16 + lr;
#pragma unroll
      for (int reg = 0; reg < 4; ++reg) {
        const int m = mg0 + reg;
        const short val = f2h(acc[mi][ni][reg] * oscale);
        if (slice < 2) {
          const int b = m >> 10, s = m & 1023, hh = ng >> 6, dh = ng & 63;
          outp[((size_t)((b * H_ + hh) * S_) + s) * DH_ + dh] = val;
        } else {
          vp[((size_t)(ng >> 10) << 20) + (size_t)m * S_ + (ng & 1023)] = val;
        }
      }
    }
}

// ----------------------------------------------------------------- attention
// Block = (b, h, z): q-tiles {qtH=15-z, qtL=z}, ONE fused sweep over KV tiles.
// K and V tiles (64x64 fp16) staged cooperatively into THREE rotating LDS
// buffers via global_load_lds w16 (proj's skeleton: counted vmcnt(4) + raw
// s_barrier per tile; XOR-granule swizzle g^(row&7) on src + read -> 2-way
// conflicts only). Waves read fragments via ds_read_b128 (no redundant
// global loads). P staged per-wave in ONE shared buffer (H then L serial;
// same-wave DS ordering makes the reuse safe).
__global__ __launch_bounds__(256, 2) void attn_fwd(
    const short* __restrict__ qp, const short* __restrict__ kp,
    const short* __restrict__ vT, const int* __restrict__ Qlen,
    const int* __restrict__ Vlen, float* __restrict__ out) {
  __shared__ __align__(16) short Ks[3][64][64];
  __shared__ __align__(16) short Vs[3][64][64];
  __shared__ short Plds[4][16][72];
  const int bid = blockIdx.x;
  const int z = bid & 7;
  const int bh = bid >> 3;
  const int h = bh & 15;
  const int b = bh >> 4;
  const int tid = threadIdx.x;
  const int lane = tid & 63;
  const int w = tid >> 6;
  const int lr = lane & 15, lg = lane >> 4;
  const short* qb = qp + (size_t)((b * H_ + h) * S_) * DH_;
  const short* kb = kp + (size_t)((b * H_ + h) * S_) * DH_;
  const short* vb = vT + (size_t)((b * H_ + h) * DH_) * S_;
  const int vlen = Vlen[b], qlen = Qlen[b];

  const int qtH = 15 - z, qtL = z;
  const int vcap = (vlen + 63) >> 6;
  const int nTH = (vlen > 0) ? min(qtH + 1, vcap) : (qtH + 1);
  const int nTL = (vlen > 0) ? min(qtL + 1, vcap) : (qtL + 1);
  const int q0H = qtH * 64 + w * 16;
  const int q0L = qtL * 64 + w * 16;

  const bool hAct = qlen > qtH * 64;
  const bool lAct = qlen > qtL * 64;
  const int tHn = hAct ? nTH : 0;
  const int tLn = lAct ? nTL : 0;
  const int tMax = (tHn > tLn) ? tHn : tLn;

  // stage map: wave w covers rows w*16..w*16+15 (i=0,1 -> 8-row halves);
  // lane: row = w*16 + i*8 + (lane>>3), granule g = lane&7; src granule
  // pre-swizzled by ^(row&7) (matches read-side swizzle involution).
  const int s_r0 = w * 16 + (lane >> 3);  // +8 for i=1
  const int s_g = lane & 7;

#define STAGEKV(buf, s)                                                       \
  do {                                                                        \
    const int kv0s = (s) * 64;                                                \
    const int r0_ = s_r0, r1_ = s_r0 + 8;                                     \
    const int sg0_ = (s_g ^ (r0_ & 7)) * 8;                                   \
    const int sg1_ = (s_g ^ (r1_ & 7)) * 8;                                   \
    GLOAD_LDS16(kb + (size_t)(kv0s + r0_) * DH_ + sg0_,                       \
                &Ks[buf][r0_][s_g * 8]);                                      \
    GLOAD_LDS16(vb + (size_t)r0_ * S_ + kv0s + sg0_, &Vs[buf][r0_][s_g * 8]); \
    GLOAD_LDS16(kb + (size_t)(kv0s + r1_) * DH_ + sg1_,                       \
                &Ks[buf][r1_][s_g * 8]);                                      \
    GLOAD_LDS16(vb + (size_t)r1_ * S_ + kv0s + sg1_, &Vs[buf][r1_][s_g * 8]); \
  } while (0)

  f16x8 qfH[2], qfL[2];
#pragma unroll
  for (int c = 0; c < 2; ++c) {
    qfH[c] = ld_frag_g(qb + (size_t)(q0H + lr) * DH_ + c * 32 + lg * 8);
    qfL[c] = ld_frag_g(qb + (size_t)(q0L + lr) * DH_ + c * 32 + lg * 8);
  }

  float lH[4], lL[4];
  f32x4 oH[4], oL[4];
#pragma unroll
  for (int rr = 0; rr < 4; ++rr) {
    lH[rr] = 0.f; lL[rr] = 0.f;
    oH[rr] = f32x4{0.f, 0.f, 0.f, 0.f};
    oL[rr] = f32x4{0.f, 0.f, 0.f, 0.f};
  }

  if (tMax > 0) {
    // prologue: stage buf0(tile0), buf1(tile min(1,tMax-1)); 8 loads in flight
    STAGEKV(0, 0);
    STAGEKV(1, (1 < tMax) ? 1 : 0);

    for (int t = 0; t < tMax; ++t) {
      const int cur = t % 3;
      if (t < tMax - 2)
        asm volatile("s_waitcnt vmcnt(4)" ::: "memory");
      else
        asm volatile("s_waitcnt vmcnt(0)" ::: "memory");
      __builtin_amdgcn_s_barrier();
      __builtin_amdgcn_sched_barrier(0);
      if (t < tMax - 2) {
        STAGEKV((t + 2) % 3, t + 2);
      }

      const int kv0 = t * 64;
      const bool hact = t < tHn;
      const bool lact = t < tLn;
      const bool km = (vlen > 0) && (vlen - kv0 < 64);

      // fragments from LDS (swizzled read = involution of staged swizzle)
      f16x8 kf[8], vf[8];
#pragma unroll
      for (int nt = 0; nt < 4; ++nt)
#pragma unroll
        for (int c = 0; c < 2; ++c)
          kf[nt * 2 + c] = ld_frag_g(
              &Ks[cur][nt * 16 + lr][((c * 4 + lg) ^ (lr & 7)) * 8]);
#pragma unroll
      for (int dt = 0; dt < 4; ++dt)
#pragma unroll
        for (int c = 0; c < 2; ++c)
          vf[dt * 2 + c] = ld_frag_g(
              &Vs[cur][dt * 16 + lr][((c * 4 + lg) ^ (lr & 7)) * 8]);

      f32x4 sH[4], sL[4];
      if (hact) {
#pragma unroll
        for (int nt = 0; nt < 4; ++nt) sH[nt] = f32x4{0.f, 0.f, 0.f, 0.f};
#pragma unroll
        for (int nt = 0; nt < 4; ++nt)
#pragma unroll
          for (int c = 0; c < 2; ++c)
            sH[nt] = __builtin_amdgcn_mfma_f32_16x16x32_f16(
                qfH[c], kf[nt * 2 + c], sH[nt], 0, 0, 0);
      }
      if (lact) {
#pragma unroll
        for (int nt = 0; nt < 4; ++nt) sL[nt] = f32x4{0.f, 0.f, 0.f, 0.f};
#pragma unroll
        for (int nt = 0; nt < 4; ++nt)
#pragma unroll
          for (int c = 0; c < 2; ++c)
            sL[nt] = __builtin_amdgcn_mfma_f32_16x16x32_f16(
                qfL[c], kf[nt * 2 + c], sL[nt], 0, 0, 0);
      }

      // ---- H half: softmax -> Plds -> PV (wave-private, in-order DS)
      if (hact) {
        if ((t == qtH) | km) {
#pragma unroll
          for (int reg = 0; reg < 4; ++reg) {
            const int qrow = q0H + lg * 4 + reg;
#pragma unroll
            for (int nt = 0; nt < 4; ++nt) {
              const int kv = kv0 + nt * 16 + lr;
              float sv = sH[nt][reg];
              if (km && kv >= vlen) sv -= 1e12f;
              if (kv > qrow) sv -= 1e12f;
              const float p = __expf(sv);
              lH[reg] += p;
              Plds[w][lg * 4 + reg][nt * 16 + lr] = f2h(p);
            }
          }
        } else {
#pragma unroll
          for (int reg = 0; reg < 4; ++reg)
#pragma unroll
            for (int nt = 0; nt < 4; ++nt) {
              const float p = __expf(sH[nt][reg]);
              lH[reg] += p;
              Plds[w][lg * 4 + reg][nt * 16 + lr] = f2h(p);
            }
        }
#pragma unroll
        for (int c = 0; c < 2; ++c) {
          s16x4 a0 = *(const s16x4*)(&Plds[w][lr][c * 32 + lg * 8]);
          s16x4 a1 = *(const s16x4*)(&Plds[w][lr][c * 32 + lg * 8 + 4]);
          s16x8 pr = {a0[0], a0[1], a0[2], a0[3], a1[0], a1[1], a1[2], a1[3]};
          f16x8 pa = __builtin_bit_cast(f16x8, pr);
#pragma unroll
          for (int dt = 0; dt < 4; ++dt)
            oH[dt] = __builtin_amdgcn_mfma_f32_16x16x32_f16(pa, vf[dt * 2 + c],
                                                            oH[dt], 0, 0, 0);
        }
      }
      // ---- L half (reuses Plds; same-wave ds_write-after-ds_read is ordered)
      if (lact) {
        if ((t == qtL) | km) {
#pragma unroll
          for (int reg = 0; reg < 4; ++reg) {
            const int qrow = q0L + lg * 4 + reg;
#pragma unroll
            for (int nt = 0; nt < 4; ++nt) {
              const int kv = kv0 + nt * 16 + lr;
              float sv = sL[nt][reg];
              if (km && kv >= vlen) sv -= 1e12f;
              if (kv > qrow) sv -= 1e12f;
              const float p = __expf(sv);
              lL[reg] += p;
              Plds[w][lg * 4 + reg][nt * 16 + lr] = f2h(p);
            }
          }
        } else {
#pragma unroll
          for (int reg = 0; reg < 4; ++reg)
#pragma unroll
            for (int nt = 0; nt < 4; ++nt) {
              const float p = __expf(sL[nt][reg]);
              lL[reg] += p;
              Plds[w][lg * 4 + reg][nt * 16 + lr] = f2h(p);
            }
        }
#pragma unroll
        for (int c = 0; c < 2; ++c) {
          s16x4 a0 = *(const s16x4*)(&Plds[w][lr][c * 32 + lg * 8]);
          s16x4 a1 = *(const s16x4*)(&Plds[w][lr][c * 32 + lg * 8 + 4]);
          s16x8 pr = {a0[0], a0[1], a0[2], a0[3], a1[0], a1[1], a1[2], a1[3]};
          f16x8 pa = __builtin_bit_cast(f16x8, pr);
#pragma unroll
          for (int dt = 0; dt < 4; ++dt)
            oL[dt] = __builtin_amdgcn_mfma_f32_16x16x32_f16(pa, vf[dt * 2 + c],
                                                            oL[dt], 0, 0, 0);
        }
      }
    }
  }
#undef STAGEKV

#pragma unroll
  for (int reg = 0; reg < 4; ++reg) {
    float ls = lH[reg];
    ls += __shfl_xor(ls, 1);
    ls += __shfl_xor(ls, 2);
    ls += __shfl_xor(ls, 4);
    ls += __shfl_xor(ls, 8);
    const int qrow = q0H + lg * 4 + reg;
    const float sc = (qrow < qlen) ? (1.f / ls) : 0.f;
#pragma unroll
    for (int dt = 0; dt < 4; ++dt)
      out[(size_t)(b * S_ + qrow) * D_ + h * DH_ + dt * 16 + lr] =
          oH[dt][reg] * sc;
  }
#pragma unroll
  for (int reg = 0; reg < 4; ++reg) {
    float ls = lL[reg];
    ls += __shfl_xor(ls, 1);
    ls += __shfl_xor(ls, 2);
    ls += __shfl_xor(ls, 4);
    ls += __shfl_xor(ls, 8);
    const int qrow = q0L + lg * 4 + reg;
    const float sc = (qrow < qlen) ? (1.f / ls) : 0.f;
#pragma unroll
    for (int dt = 0; dt < 4; ++dt)
      out[(size_t)(b * S_ + qrow) * D_ + h * DH_ + dt * 16 + lr] =
          oL[dt][reg] * sc;
  }
}

// ------------------------------------------------------------------- launch
extern "C" void kernel_launch(void* const* d_in, const int* in_sizes, int n_in,
                              void* d_out, int out_size, void* d_ws,
                              size_t ws_size, hipStream_t stream) {
  const float* Q = (const float*)d_in[0];
  const float* K = (const float*)d_in[1];
  const float* V = (const float*)d_in[2];
  const float* WQ = (const float*)d_in[3];
  const float* WK = (const float*)d_in[4];
  const float* WV = (const float*)d_in[5];
  const int* Qlen = (const int*)d_in[6];
  const int* Vlen = (const int*)d_in[7];
  float* out = (float*)d_out;

  const size_t PE = (size_t)B_ * H_ * S_ * DH_;  // 8388608 elements
  short* qp = (short*)d_ws;
  short* kp = qp + PE;
  short* vT = kp + PE;
  short* wt = vT + PE;            // 3 x 1M fp16 = 6MB
  short* xhV = wt + 3 * 1048576;  // 16MB
  int* alist = (int*)(xhV + PE);  // 1537 ints (~6KB; ws total ~70MB)
  // Q/K fp16 scratch lives in d_out (33.5MB >= 32MB); attn_fwd fully
  // overwrites d_out afterwards, so this is deterministic & safe.
  short* xhQ = (short*)d_out;
  short* xhK = xhQ + PE;

  prep<<<dim3(3841), dim3(256), 0, stream>>>(Q, K, V, WQ, WK, WV, xhQ, xhK,
                                             xhV, wt, qp, alist, Qlen, Vlen);
  proj<<<dim3(1536), dim3(256), 0, stream>>>(xhQ, xhK, xhV, wt, qp, kp, vT,
                                             alist);
  attn_fwd<<<dim3(1024), dim3(256), 0, stream>>>(qp, kp, vT, Qlen, Vlen, out);
}

// Round 24
// 85.470 us; speedup vs baseline: 1.3950x; 1.0000x over previous
//
#include <hip/hip_runtime.h>
#include <hip/hip_bf16.h>

// SelfAttention: O = softmax(mask((X_q WQ)(X_k WK)^T/8)) (X_v WV), causal +
// key-padding (V_len) + query (Q_len) masks. B=8 S=1024 D=1024 H=16 Dh=64.
//
// All intermediates FP16. Length-aware skipping + proj tile compaction
// (R20 config) + attn K/V LDS staging (proj's proven skeleton: gload_lds w16
// into 3 rotating buffers, counted vmcnt(4) + raw s_barrier, XOR-granule
// swizzle on source+read) -- kills the 4x-redundant per-wave global K/V
// loads that made attn latency-bound (MfmaUtil 3%).

#define B_  8
#define S_  1024
#define D_  1024
#define H_  16
#define DH_ 64

using f16x8  = __attribute__((ext_vector_type(8))) _Float16;
using h16x2  = __attribute__((ext_vector_type(2))) __fp16;  // cvt_pkrtz result
using s16x8  = __attribute__((ext_vector_type(8))) short;
using f32x4  = __attribute__((ext_vector_type(4))) float;
using s16x4  = __attribute__((ext_vector_type(4))) short;

__device__ inline short f2h(float x) {
  _Float16 h = (_Float16)x;  // RNE
  return __builtin_bit_cast(short, h);
}

__device__ inline unsigned pk2(float a, float b) {  // 2 fp32 -> packed 2xfp16
  h16x2 p = __builtin_amdgcn_cvt_pkrtz(a, b);
  return __builtin_bit_cast(unsigned, p);
}

__device__ inline f16x8 ld_frag_g(const short* p) {  // 16B aligned
  return __builtin_bit_cast(f16x8, *(const s16x8*)p);
}

__device__ inline int kvlim_of(int vl, int ql) {  // effective k/v length
  const int v = (vl == 0) ? S_ : vl;
  return (v < ql) ? v : ql;
}

#define GLOAD_LDS16(gsrc, ldst)                                              \
  __builtin_amdgcn_global_load_lds(                                          \
      (const __attribute__((address_space(1))) unsigned int*)(gsrc),         \
      (__attribute__((address_space(3))) unsigned int*)(ldst), 16, 0, 0)

// -------------------------------------------------------------------- prep
// blocks 0..3071   : xcvt (slice = bid>>10, 8 tokens per block); skipped
//                    q regions zero-fill qp (attn reads q unconditionally),
//                    skipped k/v regions return (never read downstream).
// blocks 3072..3839: wt_prep (Wt[slice][n][k] = W[k][n], 64x64 tiles)
// block  3840      : active-tile compaction -> alist[0..cnt-1], alist[1536]=cnt
__global__ __launch_bounds__(256) void prep(
    const float* __restrict__ Qx, const float* __restrict__ Kx,
    const float* __restrict__ Vx, const float* __restrict__ WQ,
    const float* __restrict__ WK, const float* __restrict__ WV,
    short* __restrict__ dq, short* __restrict__ dk, short* __restrict__ dv,
    short* __restrict__ wt, short* __restrict__ qp, int* __restrict__ alist,
    const int* __restrict__ Qlen, const int* __restrict__ Vlen) {
  __shared__ float t[64][65];
  __shared__ int scnt[257];
  const int bid = blockIdx.x;
  const int tid = threadIdx.x;
  if (bid == 3840) {  // ---- compaction (candidate order == old gid order)
    int ql[8], kv[8];
#pragma unroll
    for (int b = 0; b < 8; ++b) {
      ql[b] = Qlen[b];
      kv[b] = kvlim_of(Vlen[b], ql[b]);
    }
    int loc[6];
    int cnt = 0;
#pragma unroll
    for (int k = 0; k < 6; ++k) {
      const int c = tid * 6 + k;
      const int slice = c % 3, r = c / 3;
      bool act;
      if (slice < 2) {
        const int jm = r & 63;
        const int m0 = (jm & 7) * 1024 + (jm >> 3) * 128;
        const int len = slice ? kv[m0 >> 10] : ql[m0 >> 10];
        act = (m0 & 1023) < len;
      } else {
        const int jn = r >> 3;
        const int n0 = (jn & 7) * 1024 + (jn >> 3) * 128;
        act = (n0 & 1023) < kv[n0 >> 10];
      }
      if (act) loc[cnt++] = c;
    }
    scnt[tid] = cnt;
    __syncthreads();
    if (tid == 0) {
      int s = 0;
      for (int i = 0; i < 256; ++i) {
        const int v = scnt[i];
        scnt[i] = s;
        s += v;
      }
      scnt[256] = s;
    }
    __syncthreads();
    const int base = scnt[tid];
    for (int k = 0; k < cnt; ++k) alist[base + k] = loc[k];
    if (tid == 0) alist[1536] = scnt[256];
  } else if (bid < 3072) {
    const int slice = bid >> 10;
    const int tok0 = (bid & 1023) * 8;
    const int bb = tok0 >> 10, local = tok0 & 1023;
    const int ql = Qlen[bb];
    int lim;
    if (slice == 0) {
      lim = (ql + 127) & ~127;
    } else {
      lim = (kvlim_of(Vlen[bb], ql) + 127) & ~127;
    }
    if (local >= lim) {
      if (slice == 0) {  // zero-fill qp rows for these 8 tokens, all heads
        const uint4 zz = {0u, 0u, 0u, 0u};
        const int hh = tid >> 4;
        short* zp = qp + ((size_t)((bb * H_ + hh) * S_) + local) * DH_ +
                    (tid & 15) * 32;
        *(uint4*)(zp + 0) = zz;
        *(uint4*)(zp + 8) = zz;
        *(uint4*)(zp + 16) = zz;
        *(uint4*)(zp + 24) = zz;
      }
      return;
    }
    const float* src = (slice == 0) ? Qx : (slice == 1) ? Kx : Vx;
    short* dst = (slice == 0) ? dq : (slice == 1) ? dk : dv;
    const size_t base = (size_t)(bid & 1023) * 8192;
#pragma unroll
    for (int j = 0; j < 4; ++j) {
      const size_t off = base + (size_t)j * 2048 + (size_t)tid * 8;
      float4 a = *(const float4*)(src + off);
      float4 b = *(const float4*)(src + off + 4);
      uint4 u = {pk2(a.x, a.y), pk2(a.z, a.w), pk2(b.x, b.y), pk2(b.z, b.w)};
      *(uint4*)(dst + off) = u;
    }
  } else {
    const int wid = bid - 3072;
    const int slice = wid >> 8;
    const int rem = wid & 255;
    const int n0 = (rem & 15) * 64, k0 = (rem >> 4) * 64;
    const float* W = (slice == 0) ? WQ : (slice == 1) ? WK : WV;
    {
      const int r = tid >> 2, c4 = tid & 3;
#pragma unroll
      for (int j = 0; j < 4; ++j) {
        float4 v = *(const float4*)(W + (size_t)(k0 + r) * D_ + n0 + c4 * 16 +
                                    j * 4);
        t[r][c4 * 16 + j * 4 + 0] = v.x;
        t[r][c4 * 16 + j * 4 + 1] = v.y;
        t[r][c4 * 16 + j * 4 + 2] = v.z;
        t[r][c4 * 16 + j * 4 + 3] = v.w;
      }
    }
    __syncthreads();
    {
      const int rn = tid >> 2, ks = tid & 3;
      short* dst =
          wt + ((size_t)slice << 20) + (size_t)(n0 + rn) * D_ + k0 + ks * 16;
      s16x4 h[4];
#pragma unroll
      for (int g = 0; g < 4; ++g)
#pragma unroll
        for (int j = 0; j < 4; ++j) h[g][j] = f2h(t[ks * 16 + g * 4 + j][rn]);
      *(s16x4*)(dst + 0) = h[0];
      *(s16x4*)(dst + 4) = h[1];
      *(s16x4*)(dst + 8) = h[2];
      *(s16x4*)(dst + 12) = h[3];
    }
  }
}

// ---------------------------------------------------------------- projections
// 1536 launched blocks; blocks >= alist[1536] exit; the rest read their tile
// from the compacted list (all active -> CUs packed 3-deep).
__global__ __launch_bounds__(256, 3) void proj(
    const short* __restrict__ xq, const short* __restrict__ xk,
    const short* __restrict__ xv, const short* __restrict__ wt,
    short* __restrict__ qp, short* __restrict__ kp, short* __restrict__ vp,
    const int* __restrict__ alist) {
  __shared__ __align__(16) short As[3][128][32];
  __shared__ __align__(16) short Bs[3][128][32];
  const int gid = blockIdx.x;
  if (gid >= alist[1536]) return;
  const int c = alist[gid];
  const int slice = c % 3;
  const int r = c / 3;
  const int tid = threadIdx.x;
  const short* A;
  const short* Bp;
  int m0, n0;
  float oscale;
  if (slice < 2) {
    A = slice ? xk : xq;              // rows = tokens (8192)
    Bp = wt + ((size_t)slice << 20);  // rows = H*Dh (1024)
    const int jm = r & 63;            // batch = jm&7 (fast), offset = jm>>3
    m0 = (jm & 7) * 1024 + (jm >> 3) * 128;
    n0 = (r >> 6) * 128;              // n-slow: 64 blocks share one Wt slab
    oscale = slice ? 1.0f : 0.125f;
  } else {
    A = wt + ((size_t)2 << 20);  // rows = H*Dh
    Bp = xv;                     // rows = tokens (8192)
    m0 = (r & 7) * 128;          // m-fast: 8 blocks share one X token band
    const int jn = r >> 3;       // batch = jn&7 (fast), offset = jn>>3
    n0 = (jn & 7) * 1024 + (jn >> 3) * 128;
    oscale = 1.0f;
  }

  const int lane = tid & 63, w = tid >> 6;
  const int wr = w >> 1, wc = w & 1;
  const int lr = lane & 15, lg = lane >> 4;
  const int g_row = tid >> 2, g_c = tid & 3;
  const int gsw = (g_c ^ ((g_row >> 1) & 3)) * 8;  // swizzled src granule
  const int rsw = (lg ^ ((lr >> 1) & 3)) * 8;      // swizzled read granule

  const short* ga = A + (size_t)(m0 + g_row) * D_ + gsw;
  const short* gb = Bp + (size_t)(n0 + g_row) * D_ + gsw;

  f32x4 acc[4][4];
#pragma unroll
  for (int i = 0; i < 4; ++i)
#pragma unroll
    for (int j = 0; j < 4; ++j) acc[i][j] = f32x4{0.f, 0.f, 0.f, 0.f};

  // prologue: stage buf0 (kt=0) and buf1 (kt=1); 8 loads outstanding
  GLOAD_LDS16(ga, &As[0][g_row][g_c * 8]);
  GLOAD_LDS16(ga + (size_t)64 * D_, &As[0][g_row + 64][g_c * 8]);
  GLOAD_LDS16(gb, &Bs[0][g_row][g_c * 8]);
  GLOAD_LDS16(gb + (size_t)64 * D_, &Bs[0][g_row + 64][g_c * 8]);
  GLOAD_LDS16(ga + 32, &As[1][g_row][g_c * 8]);
  GLOAD_LDS16(ga + (size_t)64 * D_ + 32, &As[1][g_row + 64][g_c * 8]);
  GLOAD_LDS16(gb + 32, &Bs[1][g_row][g_c * 8]);
  GLOAD_LDS16(gb + (size_t)64 * D_ + 32, &Bs[1][g_row + 64][g_c * 8]);

  for (int kt = 0; kt < 32; ++kt) {
    const int cur = kt % 3;
    if (kt < 30)
      asm volatile("s_waitcnt vmcnt(4)" ::: "memory");
    else
      asm volatile("s_waitcnt vmcnt(0)" ::: "memory");
    __builtin_amdgcn_s_barrier();
    __builtin_amdgcn_sched_barrier(0);
    if (kt < 30) {
      const int pre = (kt + 2) % 3;
      const int k2 = (kt + 2) * 32;
      GLOAD_LDS16(ga + k2, &As[pre][g_row][g_c * 8]);
      GLOAD_LDS16(ga + (size_t)64 * D_ + k2, &As[pre][g_row + 64][g_c * 8]);
      GLOAD_LDS16(gb + k2, &Bs[pre][g_row][g_c * 8]);
      GLOAD_LDS16(gb + (size_t)64 * D_ + k2, &Bs[pre][g_row + 64][g_c * 8]);
    }

    f16x8 af[4], bf[4];
#pragma unroll
    for (int mi = 0; mi < 4; ++mi)
      af[mi] = ld_frag_g(&As[cur][wr * 64 + mi * 16 + lr][rsw]);
#pragma unroll
    for (int ni = 0; ni < 4; ++ni)
      bf[ni] = ld_frag_g(&Bs[cur][wc * 64 + ni * 16 + lr][rsw]);
#pragma unroll
    for (int mi = 0; mi < 4; ++mi)
#pragma unroll
      for (int ni = 0; ni < 4; ++ni)
        acc[mi][ni] = __builtin_amdgcn_mfma_f32_16x16x32_f16(
            af[mi], bf[ni], acc[mi][ni], 0, 0, 0);
  }

  // epilogue
  short* outp = (slice == 0) ? qp : kp;
#pragma unroll
  for (int mi = 0; mi < 4; ++mi)
#pragma unroll
    for (int ni = 0; ni < 4; ++ni) {
      const int mg0 = m0 + wr * 64 + mi * 16 + lg * 4;
      const int ng = n0 + wc * 64 + ni * 16 + lr;
#pragma unroll
      for (int reg = 0; reg < 4; ++reg) {
        const int m = mg0 + reg;
        const short val = f2h(acc[mi][ni][reg] * oscale);
        if (slice < 2) {
          const int b = m >> 10, s = m & 1023, hh = ng >> 6, dh = ng & 63;
          outp[((size_t)((b * H_ + hh) * S_) + s) * DH_ + dh] = val;
        } else {
          vp[((size_t)(ng >> 10) << 20) + (size_t)m * S_ + (ng & 1023)] = val;
        }
      }
    }
}

// ----------------------------------------------------------------- attention
// Block = (b, h, z): q-tiles {qtH=15-z, qtL=z}, ONE fused sweep over KV tiles.
// K and V tiles (64x64 fp16) staged cooperatively into THREE rotating LDS
// buffers via global_load_lds w16 (proj's skeleton: counted vmcnt(4) + raw
// s_barrier per tile; XOR-granule swizzle g^(row&7) on src + read -> 2-way
// conflicts only). Waves read fragments via ds_read_b128 (no redundant
// global loads). P staged per-wave in ONE shared buffer (H then L serial;
// same-wave DS ordering makes the reuse safe).
__global__ __launch_bounds__(256, 2) void attn_fwd(
    const short* __restrict__ qp, const short* __restrict__ kp,
    const short* __restrict__ vT, const int* __restrict__ Qlen,
    const int* __restrict__ Vlen, float* __restrict__ out) {
  __shared__ __align__(16) short Ks[3][64][64];
  __shared__ __align__(16) short Vs[3][64][64];
  __shared__ short Plds[4][16][72];
  const int bid = blockIdx.x;
  const int z = bid & 7;
  const int bh = bid >> 3;
  const int h = bh & 15;
  const int b = bh >> 4;
  const int tid = threadIdx.x;
  const int lane = tid & 63;
  const int w = tid >> 6;
  const int lr = lane & 15, lg = lane >> 4;
  const short* qb = qp + (size_t)((b * H_ + h) * S_) * DH_;
  const short* kb = kp + (size_t)((b * H_ + h) * S_) * DH_;
  const short* vb = vT + (size_t)((b * H_ + h) * DH_) * S_;
  const int vlen = Vlen[b], qlen = Qlen[b];

  const int qtH = 15 - z, qtL = z;
  const int vcap = (vlen + 63) >> 6;
  const int nTH = (vlen > 0) ? min(qtH + 1, vcap) : (qtH + 1);
  const int nTL = (vlen > 0) ? min(qtL + 1, vcap) : (qtL + 1);
  const int q0H = qtH * 64 + w * 16;
  const int q0L = qtL * 64 + w * 16;

  const bool hAct = qlen > qtH * 64;
  const bool lAct = qlen > qtL * 64;
  const int tHn = hAct ? nTH : 0;
  const int tLn = lAct ? nTL : 0;
  const int tMax = (tHn > tLn) ? tHn : tLn;

  // stage map: wave w covers rows w*16..w*16+15 (i=0,1 -> 8-row halves);
  // lane: row = w*16 + i*8 + (lane>>3), granule g = lane&7; src granule
  // pre-swizzled by ^(row&7) (matches read-side swizzle involution).
  const int s_r0 = w * 16 + (lane >> 3);  // +8 for i=1
  const int s_g = lane & 7;

#define STAGEKV(buf, s)                                                       \
  do {                                                                        \
    const int kv0s = (s) * 64;                                                \
    const int r0_ = s_r0, r1_ = s_r0 + 8;                                     \
    const int sg0_ = (s_g ^ (r0_ & 7)) * 8;                                   \
    const int sg1_ = (s_g ^ (r1_ & 7)) * 8;                                   \
    GLOAD_LDS16(kb + (size_t)(kv0s + r0_) * DH_ + sg0_,                       \
                &Ks[buf][r0_][s_g * 8]);                                      \
    GLOAD_LDS16(vb + (size_t)r0_ * S_ + kv0s + sg0_, &Vs[buf][r0_][s_g * 8]); \
    GLOAD_LDS16(kb + (size_t)(kv0s + r1_) * DH_ + sg1_,                       \
                &Ks[buf][r1_][s_g * 8]);                                      \
    GLOAD_LDS16(vb + (size_t)r1_ * S_ + kv0s + sg1_, &Vs[buf][r1_][s_g * 8]); \
  } while (0)

  f16x8 qfH[2], qfL[2];
#pragma unroll
  for (int c = 0; c < 2; ++c) {
    qfH[c] = ld_frag_g(qb + (size_t)(q0H + lr) * DH_ + c * 32 + lg * 8);
    qfL[c] = ld_frag_g(qb + (size_t)(q0L + lr) * DH_ + c * 32 + lg * 8);
  }

  float lH[4], lL[4];
  f32x4 oH[4], oL[4];
#pragma unroll
  for (int rr = 0; rr < 4; ++rr) {
    lH[rr] = 0.f; lL[rr] = 0.f;
    oH[rr] = f32x4{0.f, 0.f, 0.f, 0.f};
    oL[rr] = f32x4{0.f, 0.f, 0.f, 0.f};
  }

  if (tMax > 0) {
    // prologue: stage buf0(tile0), buf1(tile min(1,tMax-1)); 8 loads in flight
    STAGEKV(0, 0);
    STAGEKV(1, (1 < tMax) ? 1 : 0);

    for (int t = 0; t < tMax; ++t) {
      const int cur = t % 3;
      if (t < tMax - 2)
        asm volatile("s_waitcnt vmcnt(4)" ::: "memory");
      else
        asm volatile("s_waitcnt vmcnt(0)" ::: "memory");
      __builtin_amdgcn_s_barrier();
      __builtin_amdgcn_sched_barrier(0);
      if (t < tMax - 2) {
        STAGEKV((t + 2) % 3, t + 2);
      }

      const int kv0 = t * 64;
      const bool hact = t < tHn;
      const bool lact = t < tLn;
      const bool km = (vlen > 0) && (vlen - kv0 < 64);

      // fragments from LDS (swizzled read = involution of staged swizzle)
      f16x8 kf[8], vf[8];
#pragma unroll
      for (int nt = 0; nt < 4; ++nt)
#pragma unroll
        for (int c = 0; c < 2; ++c)
          kf[nt * 2 + c] = ld_frag_g(
              &Ks[cur][nt * 16 + lr][((c * 4 + lg) ^ (lr & 7)) * 8]);
#pragma unroll
      for (int dt = 0; dt < 4; ++dt)
#pragma unroll
        for (int c = 0; c < 2; ++c)
          vf[dt * 2 + c] = ld_frag_g(
              &Vs[cur][dt * 16 + lr][((c * 4 + lg) ^ (lr & 7)) * 8]);

      f32x4 sH[4], sL[4];
      if (hact) {
#pragma unroll
        for (int nt = 0; nt < 4; ++nt) sH[nt] = f32x4{0.f, 0.f, 0.f, 0.f};
#pragma unroll
        for (int nt = 0; nt < 4; ++nt)
#pragma unroll
          for (int c = 0; c < 2; ++c)
            sH[nt] = __builtin_amdgcn_mfma_f32_16x16x32_f16(
                qfH[c], kf[nt * 2 + c], sH[nt], 0, 0, 0);
      }
      if (lact) {
#pragma unroll
        for (int nt = 0; nt < 4; ++nt) sL[nt] = f32x4{0.f, 0.f, 0.f, 0.f};
#pragma unroll
        for (int nt = 0; nt < 4; ++nt)
#pragma unroll
          for (int c = 0; c < 2; ++c)
            sL[nt] = __builtin_amdgcn_mfma_f32_16x16x32_f16(
                qfL[c], kf[nt * 2 + c], sL[nt], 0, 0, 0);
      }

      // ---- H half: softmax -> Plds -> PV (wave-private, in-order DS)
      if (hact) {
        if ((t == qtH) | km) {
#pragma unroll
          for (int reg = 0; reg < 4; ++reg) {
            const int qrow = q0H + lg * 4 + reg;
#pragma unroll
            for (int nt = 0; nt < 4; ++nt) {
              const int kv = kv0 + nt * 16 + lr;
              float sv = sH[nt][reg];
              if (km && kv >= vlen) sv -= 1e12f;
              if (kv > qrow) sv -= 1e12f;
              const float p = __expf(sv);
              lH[reg] += p;
              Plds[w][lg * 4 + reg][nt * 16 + lr] = f2h(p);
            }
          }
        } else {
#pragma unroll
          for (int reg = 0; reg < 4; ++reg)
#pragma unroll
            for (int nt = 0; nt < 4; ++nt) {
              const float p = __expf(sH[nt][reg]);
              lH[reg] += p;
              Plds[w][lg * 4 + reg][nt * 16 + lr] = f2h(p);
            }
        }
#pragma unroll
        for (int c = 0; c < 2; ++c) {
          s16x4 a0 = *(const s16x4*)(&Plds[w][lr][c * 32 + lg * 8]);
          s16x4 a1 = *(const s16x4*)(&Plds[w][lr][c * 32 + lg * 8 + 4]);
          s16x8 pr = {a0[0], a0[1], a0[2], a0[3], a1[0], a1[1], a1[2], a1[3]};
          f16x8 pa = __builtin_bit_cast(f16x8, pr);
#pragma unroll
          for (int dt = 0; dt < 4; ++dt)
            oH[dt] = __builtin_amdgcn_mfma_f32_16x16x32_f16(pa, vf[dt * 2 + c],
                                                            oH[dt], 0, 0, 0);
        }
      }
      // ---- L half (reuses Plds; same-wave ds_write-after-ds_read is ordered)
      if (lact) {
        if ((t == qtL) | km) {
#pragma unroll
          for (int reg = 0; reg < 4; ++reg) {
            const int qrow = q0L + lg * 4 + reg;
#pragma unroll
            for (int nt = 0; nt < 4; ++nt) {
              const int kv = kv0 + nt * 16 + lr;
              float sv = sL[nt][reg];
              if (km && kv >= vlen) sv -= 1e12f;
              if (kv > qrow) sv -= 1e12f;
              const float p = __expf(sv);
              lL[reg] += p;
              Plds[w][lg * 4 + reg][nt * 16 + lr] = f2h(p);
            }
          }
        } else {
#pragma unroll
          for (int reg = 0; reg < 4; ++reg)
#pragma unroll
            for (int nt = 0; nt < 4; ++nt) {
              const float p = __expf(sL[nt][reg]);
              lL[reg] += p;
              Plds[w][lg * 4 + reg][nt * 16 + lr] = f2h(p);
            }
        }
#pragma unroll
        for (int c = 0; c < 2; ++c) {
          s16x4 a0 = *(const s16x4*)(&Plds[w][lr][c * 32 + lg * 8]);
          s16x4 a1 = *(const s16x4*)(&Plds[w][lr][c * 32 + lg * 8 + 4]);
          s16x8 pr = {a0[0], a0[1], a0[2], a0[3], a1[0], a1[1], a1[2], a1[3]};
          f16x8 pa = __builtin_bit_cast(f16x8, pr);
#pragma unroll
          for (int dt = 0; dt < 4; ++dt)
            oL[dt] = __builtin_amdgcn_mfma_f32_16x16x32_f16(pa, vf[dt * 2 + c],
                                                            oL[dt], 0, 0, 0);
        }
      }
    }
  }
#undef STAGEKV

#pragma unroll
  for (int reg = 0; reg < 4; ++reg) {
    float ls = lH[reg];
    ls += __shfl_xor(ls, 1);
    ls += __shfl_xor(ls, 2);
    ls += __shfl_xor(ls, 4);
    ls += __shfl_xor(ls, 8);
    const int qrow = q0H + lg * 4 + reg;
    const float sc = (qrow < qlen) ? (1.f / ls) : 0.f;
#pragma unroll
    for (int dt = 0; dt < 4; ++dt)
      out[(size_t)(b * S_ + qrow) * D_ + h * DH_ + dt * 16 + lr] =
          oH[dt][reg] * sc;
  }
#pragma unroll
  for (int reg = 0; reg < 4; ++reg) {
    float ls = lL[reg];
    ls += __shfl_xor(ls, 1);
    ls += __shfl_xor(ls, 2);
    ls += __shfl_xor(ls, 4);
    ls += __shfl_xor(ls, 8);
    const int qrow = q0L + lg * 4 + reg;
    const float sc = (qrow < qlen) ? (1.f / ls) : 0.f;
#pragma unroll
    for (int dt = 0; dt < 4; ++dt)
      out[(size_t)(b * S_ + qrow) * D_ + h * DH_ + dt * 16 + lr] =
          oL[dt][reg] * sc;
  }
}

// ------------------------------------------------------------------- launch
extern "C" void kernel_launch(void* const* d_in, const int* in_sizes, int n_in,
                              void* d_out, int out_size, void* d_ws,
                              size_t ws_size, hipStream_t stream) {
  const float* Q = (const float*)d_in[0];
  const float* K = (const float*)d_in[1];
  const float* V = (const float*)d_in[2];
  const float* WQ = (const float*)d_in[3];
  const float* WK = (const float*)d_in[4];
  const float* WV = (const float*)d_in[5];
  const int* Qlen = (const int*)d_in[6];
  const int* Vlen = (const int*)d_in[7];
  float* out = (float*)d_out;

  const size_t PE = (size_t)B_ * H_ * S_ * DH_;  // 8388608 elements
  short* qp = (short*)d_ws;
  short* kp = qp + PE;
  short* vT = kp + PE;
  short* wt = vT + PE;            // 3 x 1M fp16 = 6MB
  short* xhV = wt + 3 * 1048576;  // 16MB
  int* alist = (int*)(xhV + PE);  // 1537 ints (~6KB; ws total ~70MB)
  // Q/K fp16 scratch lives in d_out (33.5MB >= 32MB); attn_fwd fully
  // overwrites d_out afterwards, so this is deterministic & safe.
  short* xhQ = (short*)d_out;
  short* xhK = xhQ + PE;

  prep<<<dim3(3841), dim3(256), 0, stream>>>(Q, K, V, WQ, WK, WV, xhQ, xhK,
                                             xhV, wt, qp, alist, Qlen, Vlen);
  proj<<<dim3(1536), dim3(256), 0, stream>>>(xhQ, xhK, xhV, wt, qp, kp, vT,
                                             alist);
  attn_fwd<<<dim3(1024), dim3(256), 0, stream>>>(qp, kp, vT, Qlen, Vlen, out);
}